// Round 1
// baseline (499.217 us; speedup 1.0000x reference)
//
#include <hip/hip_runtime.h>
#include <hip/hip_bf16.h>

#define NPTS    524288
#define NG      64
#define GSZ     64
#define VOX     (GSZ*GSZ*GSZ)       // 262144
#define NODES   64
#define TILE    64                  // points per block
#define NBLK    (NPTS / TILE)       // 8192
#define K0      192                 // padded K for layer-0 (164 -> 192)
#define FROW    384                 // Fsh row stride in BYTES (192 bf16)
#define WLCAP   1022                // worklist cap; overflow gathered inline
#define NCELL   4096                // 16^3 Morton cells
#define PREP_VB 16384               // vox-repack blocks in prep_fused
#define PREP_CB 2048                // sort-count blocks in prep_fused

typedef __attribute__((ext_vector_type(8))) short bf16x8;
typedef __attribute__((ext_vector_type(4))) float f32x4;

__device__ inline unsigned short f2bf(float f) {
    __hip_bfloat16 b = __float2bfloat16(f);
    union { __hip_bfloat16 h; unsigned short u; } cv; cv.h = b;
    return cv.u;
}
__device__ inline unsigned int pk2(float c0, float c1) {
    return (unsigned int)f2bf(c0) | ((unsigned int)f2bf(c1) << 16);
}
__device__ inline float bflo(unsigned int v) { return __uint_as_float(v << 16); }
__device__ inline float bfhi(unsigned int v) { return __uint_as_float(v & 0xffff0000u); }

// XOR-swizzled Fsh byte address: row stride 384B == bank-period 0, so XOR the
// 16B-chunk index (byte bits 4-6) with row&7 to spread MFMA fragment reads
// across all 32 banks (stays within the row's 128B group -> bijective, in-row).
__device__ inline int fsh_addr(int row, int col2) {
    return row * FROW + (col2 ^ ((row & 7) << 4));
}

__device__ inline int spread4(int v) {   // 4 bits -> bits 0,3,6,9
    return (v & 1) | ((v & 2) << 2) | ((v & 4) << 4) | ((v & 8) << 6);
}
__device__ inline int cell_of(float px, float py, float pz) {
    int cx = min(max((int)((px + 1.0f) * 8.0f), 0), 15);
    int cy = min(max((int)((py + 1.0f) * 8.0f), 0), 15);
    int cz = min(max((int)((pz + 1.0f) * 8.0f), 0), 15);
    return spread4(cx) | (spread4(cy) << 1) | (spread4(cz) << 2);
}

// ---- fused prep: vox repack + sort histogram + weight/transform prep ----
// hist must be zeroed (hipMemsetAsync) before this kernel.
__global__ void prep_fused(const float* __restrict__ fg, uint4* __restrict__ vox4,
                           const float* __restrict__ x, unsigned short* __restrict__ cid,
                           int* __restrict__ hist,
                           const float* __restrict__ W0, const float* __restrict__ W1,
                           const float* __restrict__ gscale, const float* __restrict__ gtrans,
                           unsigned short* __restrict__ w0t, unsigned short* __restrict__ w1t,
                           float* __restrict__ ptab) {
    int b = blockIdx.x;
    int tid = threadIdx.x;
    if (b < PREP_VB) {
        // vox repack: [G,C,64^3] fp32 -> [G,64^3] packed bf16x2
        int idx = b * 256 + tid;
        int g = idx >> 16;
        int v = (idx & 65535) * 4;
        const float* basep = fg + (size_t)g * (2 * VOX) + v;
        float4 a = *(const float4*)basep;
        float4 c = *(const float4*)(basep + VOX);
        vox4[idx] = make_uint4(pk2(a.x, c.x), pk2(a.y, c.y), pk2(a.z, c.z), pk2(a.w, c.w));
    } else if (b < PREP_VB + PREP_CB) {
        // per-point cell id + global histogram
        int p = (b - PREP_VB) * 256 + tid;
        int c = cell_of(x[p * 3 + 0], x[p * 3 + 1], x[p * 3 + 2]);
        cid[p] = (unsigned short)c;
        atomicAdd(&hist[c], 1);
    } else {
        // weights transpose to bf16 + packed transform table
        int t = (b - PREP_VB - PREP_CB) * 256 + tid;   // 0..4095
        for (int i = t; i < NODES * K0; i += 4096) {
            int n = i / K0, k = i - n * K0;
            w0t[i] = (k < 164) ? f2bf(W0[k * NODES + n]) : (unsigned short)0;
        }
        for (int i = t; i < NODES * NODES; i += 4096) {
            int n = i >> 6, k = i & 63;
            w1t[i] = f2bf(W1[k * NODES + n]);
        }
        if (t < NG) {
            // ptab[g] = {sx,sy,sz,0, tx+1,ty+1,tz+1,0}; main computes
            // ix = fma(px, s, t1) * 31.5f  (arithmetic kept close to original)
            ptab[t * 8 + 0] = gscale[t * 3 + 0];
            ptab[t * 8 + 1] = gscale[t * 3 + 1];
            ptab[t * 8 + 2] = gscale[t * 3 + 2];
            ptab[t * 8 + 3] = 0.0f;
            ptab[t * 8 + 4] = gtrans[t * 3 + 0] + 1.0f;
            ptab[t * 8 + 5] = gtrans[t * 3 + 1] + 1.0f;
            ptab[t * 8 + 6] = gtrans[t * 3 + 2] + 1.0f;
            ptab[t * 8 + 7] = 0.0f;
        }
    }
}

// ---- sort 2: exclusive scan of 4096 bins (1 block, 256 threads x 16 bins) ----
__global__ void sort_scan(const int* __restrict__ hist, int* __restrict__ offs) {
    __shared__ int partial[256];
    int t = threadIdx.x;
    int loc[16];
    int s = 0;
    #pragma unroll
    for (int i = 0; i < 16; ++i) { loc[i] = s; s += hist[t * 16 + i]; }
    partial[t] = s;
    __syncthreads();
    for (int d = 1; d < 256; d <<= 1) {
        int v = (t >= d) ? partial[t - d] : 0;
        __syncthreads();
        partial[t] += v;
        __syncthreads();
    }
    int base = partial[t] - s;      // exclusive
    #pragma unroll
    for (int i = 0; i < 16; ++i) offs[t * 16 + i] = base + loc[i];
}

// ---- sort 3: scatter points to sorted order (destroys offs) ----
__global__ void sort_scatter(const float* __restrict__ x, const unsigned short* __restrict__ cell_id,
                             int* __restrict__ offs, float4* __restrict__ spts) {
    int p = blockIdx.x * blockDim.x + threadIdx.x;
    int c = cell_id[p];
    int pos = atomicAdd(&offs[c], 1);
    spts[pos] = make_float4(x[p * 3 + 0], x[p * 3 + 1], x[p * 3 + 2], __int_as_float(p));
}

// ---- gather one (pt, g) pair -> packed feature in Fsh (swizzled) ----
__device__ inline void gather_pair(int pt, int g, float ix, float iy, float iz,
                                   const unsigned int* __restrict__ vox,
                                   unsigned char* FshB) {
    float fx = floorf(ix), fy = floorf(iy), fz = floorf(iz);
    int x0 = (int)fx, y0 = (int)fy, z0 = (int)fz;
    float wx = ix - fx, wy = iy - fy, wz = iz - fz;
    float wxa0 = (x0 >= 0) ? (1.0f - wx) : 0.0f;
    float wxa1 = (x0 < 63) ? wx : 0.0f;
    float wya0 = (y0 >= 0) ? (1.0f - wy) : 0.0f;
    float wya1 = (y0 < 63) ? wy : 0.0f;
    float wza0 = (z0 >= 0) ? (1.0f - wz) : 0.0f;
    float wza1 = (z0 < 63) ? wz : 0.0f;
    int xc0 = max(x0, 0), xc1 = min(x0 + 1, 63);
    int yc0 = max(y0, 0), yc1 = min(y0 + 1, 63);
    int zc0 = max(z0, 0), zc1 = min(z0 + 1, 63);
    const unsigned int* vg = vox + ((size_t)g << 18);
    float f0 = 0.f, f1 = 0.f;
    #pragma unroll
    for (int dz = 0; dz < 2; ++dz) {
        int zc = dz ? zc1 : zc0; float wzv = dz ? wza1 : wza0;
        #pragma unroll
        for (int dy = 0; dy < 2; ++dy) {
            int yc = dy ? yc1 : yc0; float wyv = dy ? wya1 : wya0;
            int rowb = ((zc << 6) + yc) << 6;
            float wzy = wzv * wyv;
            unsigned int v0 = vg[rowb + xc0], v1 = vg[rowb + xc1];
            f0 += wzy * (wxa0 * bflo(v0) + wxa1 * bflo(v1));
            f1 += wzy * (wxa0 * bfhi(v0) + wxa1 * bfhi(v1));
        }
    }
    *(unsigned int*)&FshB[fsh_addr(pt, 72 + 4 * g)] = pk2(f0, f1);
}

// ---- main fused kernel (sorted points, indirect output) ----
// LDS = 24576 (Fsh) + 2048 (wlbuf) = 26624 B = 26 KiB -> 6 blocks/CU, 24 waves/CU
__global__ void __launch_bounds__(256, 6)
amrsrn_main(const float4* __restrict__ spts,
            const float* __restrict__ ptab,
            const unsigned int* __restrict__ vox,
            const unsigned short* __restrict__ w0t,
            const unsigned short* __restrict__ w1t,
            const float* __restrict__ b0,
            const float* __restrict__ b1,
            const float* __restrict__ W2,
            const float* __restrict__ b2,
            float* __restrict__ out) {
    __shared__ __align__(16) unsigned char FshB[TILE * FROW];   // 24576 B
    __shared__ __align__(8) unsigned short wlbuf[1024];         // 2048 B: [0:2)=cnt, entries at +2
    int* const cntp = (int*)wlbuf;

    const int tid = threadIdx.x;
    const int lane = tid & 63;
    // XCD swizzle: round-robin dispatch -> each XCD gets a contiguous Morton range
    const int cb = ((blockIdx.x & 7) << 10) | (blockIdx.x >> 3);
    const int base = cb * TILE;

    // ---- phase 0: zero Fsh ----
    for (int i = tid; i < TILE * FROW / 16; i += 256) ((uint4*)FshB)[i] = make_uint4(0, 0, 0, 0);
    if (tid == 0) *cntp = 0;

    // own point (pt = tid & 63), straight from global (L1-hot, 1 KiB/block)
    const int pt = tid & 63;
    float4 sp = spts[base + pt];
    const float px = sp.x, py = sp.y, pz = sp.z;
    __syncthreads();

    // ---- phase 1a: positional encoding (cols 0..35) ----
    {
        int grp = tid >> 6;
        #pragma unroll
        for (int t = 0; t < 9; ++t) {
            int tau = grp * 9 + t;
            int tt = (tau < 18) ? tau : tau - 18;
            int l = tt / 3, d = tt - l * 3;
            float c = (d == 0) ? px : ((d == 1) ? py : pz);
            float ang = c * (3.14159265358979323846f * (float)(1 << l));
            float val = (tau < 18) ? __sinf(ang) : __cosf(ang);
            *(unsigned short*)&FshB[fsh_addr(pt, tau * 2)] = f2bf(val);
        }
    }

    // ---- phase 1b: scan 64x64 pairs -> worklist ----
    {
        int gbase = (tid >> 6) * 16;
        for (int gi = 0; gi < 16; ++gi) {
            int g = gbase + gi;
            float4 pa = *(const float4*)&ptab[g * 8];       // wave-uniform addr -> L1 broadcast
            float4 pb = *(const float4*)&ptab[g * 8 + 4];
            float ix = fmaf(px, pa.x, pb.x) * 31.5f;
            float iy = fmaf(py, pa.y, pb.y) * 31.5f;
            float iz = fmaf(pz, pa.z, pb.z) * 31.5f;
            bool valid = (ix >= -1.0f) & (ix < 64.0f)
                       & (iy >= -1.0f) & (iy < 64.0f)
                       & (iz >= -1.0f) & (iz < 64.0f);
            unsigned long long m = __ballot(valid);
            if (m) {
                int b = 0;
                if (lane == 0) b = atomicAdd(cntp, __popcll(m));
                b = __shfl(b, 0);
                if (valid) {
                    int slot = b + __popcll(m & ((1ull << lane) - 1ull));
                    if (slot < WLCAP) wlbuf[2 + slot] = (unsigned short)((pt << 6) | g);
                    else gather_pair(pt, g, ix, iy, iz, vox, FshB);
                }
            }
        }
    }
    __syncthreads();

    // ---- phase 2: process worklist ----
    {
        int n = min(*cntp, WLCAP);
        for (int i = tid; i < n; i += 256) {
            int e = wlbuf[2 + i];
            int ept = e >> 6, eg = e & 63;
            float4 s2 = spts[base + ept];
            float4 pa = *(const float4*)&ptab[eg * 8];
            float4 pb = *(const float4*)&ptab[eg * 8 + 4];
            float ix = fmaf(s2.x, pa.x, pb.x) * 31.5f;
            float iy = fmaf(s2.y, pa.y, pb.y) * 31.5f;
            float iz = fmaf(s2.z, pa.z, pb.z) * 31.5f;
            gather_pair(ept, eg, ix, iy, iz, vox, FshB);
        }
    }
    __syncthreads();

    // ---- phase 3: MFMA MLP. wave w owns pts [16w, 16w+16) ----
    const int wv = tid >> 6;
    const int ptb = wv * 16;
    const int row = lane & 15;
    const int quad = lane >> 4;

    f32x4 acc0[4] = {{0,0,0,0},{0,0,0,0},{0,0,0,0},{0,0,0,0}};
    #pragma unroll
    for (int ks = 0; ks < 6; ++ks) {
        bf16x8 a = *(const bf16x8*)&FshB[fsh_addr(ptb + row, ks * 64 + quad * 16)];
        #pragma unroll
        for (int nt = 0; nt < 4; ++nt) {
            bf16x8 b = *(const bf16x8*)&w0t[(nt * 16 + row) * K0 + ks * 32 + quad * 8];
            acc0[nt] = __builtin_amdgcn_mfma_f32_16x16x32_bf16(a, b, acc0[nt], 0, 0, 0);
        }
    }
    #pragma unroll
    for (int nt = 0; nt < 4; ++nt) {
        int node = nt * 16 + row;
        float bb = b0[node];
        #pragma unroll
        for (int r = 0; r < 4; ++r) {
            float h = acc0[nt][r] + bb;
            float s = __sinf(h);
            h = 0.5f * h + s * s;
            *(unsigned short*)&FshB[fsh_addr(ptb + quad * 4 + r, 2 * node)] = f2bf(h);
        }
    }

    f32x4 acc1[4] = {{0,0,0,0},{0,0,0,0},{0,0,0,0},{0,0,0,0}};
    #pragma unroll
    for (int ks = 0; ks < 2; ++ks) {
        bf16x8 a = *(const bf16x8*)&FshB[fsh_addr(ptb + row, ks * 64 + quad * 16)];
        #pragma unroll
        for (int nt = 0; nt < 4; ++nt) {
            bf16x8 b = *(const bf16x8*)&w1t[(nt * 16 + row) * NODES + ks * 32 + quad * 8];
            acc1[nt] = __builtin_amdgcn_mfma_f32_16x16x32_bf16(a, b, acc1[nt], 0, 0, 0);
        }
    }
    float part[4] = {0.f, 0.f, 0.f, 0.f};
    #pragma unroll
    for (int nt = 0; nt < 4; ++nt) {
        int node = nt * 16 + row;
        float b1v = b1[node];
        float w2v = W2[node];
        #pragma unroll
        for (int r = 0; r < 4; ++r) {
            float h = acc1[nt][r] + b1v;
            float s = __sinf(h);
            h = 0.5f * h + s * s;
            part[r] += h * w2v;
        }
    }
    #pragma unroll
    for (int m = 1; m < 16; m <<= 1) {
        #pragma unroll
        for (int r = 0; r < 4; ++r) part[r] += __shfl_xor(part[r], m);
    }
    if (row == 0) {
        float b2v = b2[0];
        #pragma unroll
        for (int r = 0; r < 4; ++r) {
            int p2 = ptb + quad * 4 + r;
            float4 so = spts[base + p2];
            out[__float_as_int(so.w)] = part[r] + b2v;
        }
    }
}

// ---- fallback (no workspace): direct fp32 kernel ----
__global__ void amrsrn_fallback(const float* __restrict__ x,
                                const float* __restrict__ gscale,
                                const float* __restrict__ gtrans,
                                const float* __restrict__ fg,
                                const float* __restrict__ W0,
                                const float* __restrict__ b0,
                                const float* __restrict__ W1,
                                const float* __restrict__ b1,
                                const float* __restrict__ W2,
                                const float* __restrict__ b2,
                                float* __restrict__ out) {
    int p = blockIdx.x * blockDim.x + threadIdx.x;
    float px = x[p*3+0], py = x[p*3+1], pz = x[p*3+2];
    float h0[NODES];
    #pragma unroll
    for (int j = 0; j < NODES; ++j) h0[j] = b0[j];
    #pragma unroll
    for (int l = 0; l < 6; ++l) {
        float freq = 3.14159265358979323846f * (float)(1 << l);
        #pragma unroll
        for (int d = 0; d < 3; ++d) {
            float v = (d == 0 ? px : (d == 1 ? py : pz)) * freq;
            float s = __sinf(v), c = __cosf(v);
            const float* wrs = W0 + (l*3 + d) * NODES;
            const float* wrc = W0 + (18 + l*3 + d) * NODES;
            #pragma unroll
            for (int j = 0; j < NODES; ++j) h0[j] += s * wrs[j] + c * wrc[j];
        }
    }
    for (int g = 0; g < NG; ++g) {
        float ix = (px * gscale[g*3+0] + gtrans[g*3+0] + 1.0f) * 31.5f;
        float iy = (py * gscale[g*3+1] + gtrans[g*3+1] + 1.0f) * 31.5f;
        float iz = (pz * gscale[g*3+2] + gtrans[g*3+2] + 1.0f) * 31.5f;
        float fxf = floorf(ix), fyf = floorf(iy), fzf = floorf(iz);
        int x0 = (int)fxf, y0 = (int)fyf, z0 = (int)fzf;
        float wx = ix - fxf, wy = iy - fyf, wz = iz - fzf;
        bool any = (x0 >= -1 && x0 < GSZ) && (y0 >= -1 && y0 < GSZ) && (z0 >= -1 && z0 < GSZ);
        if (any) {
            float f0 = 0.f, f1 = 0.f;
            #pragma unroll
            for (int dz = 0; dz < 2; ++dz) {
                int zi = z0 + dz; bool vz = ((unsigned)zi < (unsigned)GSZ);
                int zc = min(max(zi, 0), GSZ - 1);
                float wzf = dz ? wz : 1.f - wz;
                #pragma unroll
                for (int dy = 0; dy < 2; ++dy) {
                    int yi = y0 + dy; bool vy = ((unsigned)yi < (unsigned)GSZ);
                    int yc = min(max(yi, 0), GSZ - 1);
                    float wyf = dy ? wy : 1.f - wy;
                    int rowoff = (zc * GSZ + yc) * GSZ;
                    #pragma unroll
                    for (int dx = 0; dx < 2; ++dx) {
                        int xi = x0 + dx; bool vx = ((unsigned)xi < (unsigned)GSZ);
                        int xc = min(max(xi, 0), GSZ - 1);
                        float w = wzf * wyf * (dx ? wx : 1.f - wx);
                        w = (vz && vy && vx) ? w : 0.f;
                        const float* gp = fg + ((size_t)g << 19);
                        f0 += w * gp[rowoff + xc];
                        f1 += w * gp[VOX + rowoff + xc];
                    }
                }
            }
            const float* wr = W0 + (36 + 2*g) * NODES;
            #pragma unroll
            for (int j = 0; j < NODES; ++j) h0[j] += f0 * wr[j] + f1 * wr[NODES + j];
        }
    }
    #pragma unroll
    for (int j = 0; j < NODES; ++j) { float s = __sinf(h0[j]); h0[j] = 0.5f * h0[j] + s * s; }
    float out_acc = b2[0];
    #pragma unroll
    for (int half = 0; half < 2; ++half) {
        float h1[32];
        #pragma unroll
        for (int j = 0; j < 32; ++j) h1[j] = b1[half*32 + j];
        #pragma unroll
        for (int i = 0; i < NODES; ++i) {
            float a = h0[i];
            const float* w1r = W1 + i * NODES + half*32;
            #pragma unroll
            for (int j = 0; j < 32; ++j) h1[j] += a * w1r[j];
        }
        #pragma unroll
        for (int j = 0; j < 32; ++j) { float s = __sinf(h1[j]); out_acc += (0.5f * h1[j] + s * s) * W2[half*32 + j]; }
    }
    out[p] = out_acc;
}

extern "C" void kernel_launch(void* const* d_in, const int* in_sizes, int n_in,
                              void* d_out, int out_size, void* d_ws, size_t ws_size,
                              hipStream_t stream) {
    const float* x      = (const float*)d_in[0];
    const float* gscale = (const float*)d_in[1];
    const float* gtrans = (const float*)d_in[2];
    const float* fg     = (const float*)d_in[3];
    const float* W0     = (const float*)d_in[4];
    const float* b0     = (const float*)d_in[5];
    const float* W1     = (const float*)d_in[6];
    const float* b1     = (const float*)d_in[7];
    const float* W2     = (const float*)d_in[8];
    const float* b2     = (const float*)d_in[9];
    float* out = (float*)d_out;

    // workspace layout (all within 128 MiB):
    //   [0,       24576)  w0t
    //   [24576,   32768)  w1t
    //   [32768,   34816)  ptab (64 x 8 floats)
    //   [64K,     80K)    hist (4096 int)
    //   [80K,     96K)    offs (4096 int)
    //   [96K,     96K+1M) cell_id (524288 u16)
    //   [+,       +8M)    sorted pts (524288 float4)
    //   [+,       +64M)   vox
    char* wsp = (char*)d_ws;
    unsigned short* w0t = (unsigned short*)wsp;
    unsigned short* w1t = w0t + NODES * K0;
    float* ptab         = (float*)(wsp + 32768);
    int* hist           = (int*)(wsp + (64 << 10));
    int* offs           = (int*)(wsp + (80 << 10));
    unsigned short* cid = (unsigned short*)(wsp + (96 << 10));
    float4* spts        = (float4*)(wsp + (96 << 10) + (1 << 20));
    unsigned int* vox   = (unsigned int*)(wsp + (96 << 10) + (1 << 20) + (8 << 20));
    const size_t ws_needed = (96 << 10) + (1 << 20) + (8 << 20) + (size_t)NG * VOX * 4;

    if (ws_size >= ws_needed) {
        hipMemsetAsync(hist, 0, NCELL * sizeof(int), stream);
        prep_fused<<<PREP_VB + PREP_CB + 16, 256, 0, stream>>>(
            fg, (uint4*)vox, x, cid, hist, W0, W1, gscale, gtrans, w0t, w1t, ptab);
        sort_scan<<<1, 256, 0, stream>>>(hist, offs);
        sort_scatter<<<NPTS / 256, 256, 0, stream>>>(x, cid, offs, spts);
        amrsrn_main<<<NBLK, 256, 0, stream>>>(spts, ptab, vox,
                                              w0t, w1t, b0, b1, W2, b2, out);
    } else {
        amrsrn_fallback<<<NPTS / 256, 256, 0, stream>>>(
            x, gscale, gtrans, fg, W0, b0, W1, b1, W2, b2, out);
    }
}

// Round 2
// 449.375 us; speedup vs baseline: 1.1109x; 1.1109x over previous
//
#include <hip/hip_runtime.h>
#include <hip/hip_bf16.h>

#define NPTS    524288
#define NG      64
#define GSZ     64
#define VOX     (GSZ*GSZ*GSZ)       // 262144
#define NODES   64
#define TILE    64                  // points per block
#define NBLK    (NPTS / TILE)       // 8192
#define K0      192                 // padded K for layer-0 (164 -> 192)
#define SF      200                 // Fsh row stride (bf16) - natural bank stagger
#define WLCAP   2048                // worklist cap; overflow gathered inline
#define NCELL   4096                // 16^3 Morton cells
#define PREP_VB 16384               // vox-repack blocks in prep_fused
#define PREP_CB 2048                // sort-count blocks in prep_fused

typedef __attribute__((ext_vector_type(8))) short bf16x8;
typedef __attribute__((ext_vector_type(4))) float f32x4;

__device__ inline unsigned short f2bf(float f) {
    __hip_bfloat16 b = __float2bfloat16(f);
    union { __hip_bfloat16 h; unsigned short u; } cv; cv.h = b;
    return cv.u;
}
__device__ inline unsigned int pk2(float c0, float c1) {
    return (unsigned int)f2bf(c0) | ((unsigned int)f2bf(c1) << 16);
}
__device__ inline float bflo(unsigned int v) { return __uint_as_float(v << 16); }
__device__ inline float bfhi(unsigned int v) { return __uint_as_float(v & 0xffff0000u); }

__device__ inline int spread4(int v) {   // 4 bits -> bits 0,3,6,9
    return (v & 1) | ((v & 2) << 2) | ((v & 4) << 4) | ((v & 8) << 6);
}
__device__ inline int cell_of(float px, float py, float pz) {
    int cx = min(max((int)((px + 1.0f) * 8.0f), 0), 15);
    int cy = min(max((int)((py + 1.0f) * 8.0f), 0), 15);
    int cz = min(max((int)((pz + 1.0f) * 8.0f), 0), 15);
    return spread4(cx) | (spread4(cy) << 1) | (spread4(cz) << 2);
}

// Bricked vox layout: 2x2x2-voxel bricks (8 u32 = 32B), bricks linear in
// (bz,by,bx).  idx = (bz<<13 | by<<8 | bx<<3) + (lz<<2 | ly<<1 | lx).
// A 128B cache line covers an 8x2x2 voxel region (vs 32x1x1 for linear),
// cutting distinct-line requests per trilinear-gather wave ~2-4x.

// ---- fused prep: vox brick-repack + sort histogram + weight prep ----
// hist must be zeroed (hipMemsetAsync) before this kernel.
__global__ void prep_fused(const float* __restrict__ fg, uint4* __restrict__ vox4,
                           const float* __restrict__ x, unsigned short* __restrict__ cid,
                           int* __restrict__ hist,
                           const float* __restrict__ W0, const float* __restrict__ W1,
                           unsigned short* __restrict__ w0t, unsigned short* __restrict__ w1t) {
    int b = blockIdx.x;
    int tid = threadIdx.x;
    if (b < PREP_VB) {
        // each thread writes one uint4 = half-brick (fixed lz), coalesced out
        int idx = b * 256 + tid;            // NG * VOX/4 total
        int g = idx >> 16;                   // 65536 half-bricks per grid
        int hb = idx & 65535;
        int brick = hb >> 1;
        int h = hb & 1;                      // lz
        int bx = brick & 31, by = (brick >> 5) & 31, bz = brick >> 10;
        int xx = bx << 1, yy = by << 1, zz = (bz << 1) + h;
        const float* c0 = fg + (size_t)g * (2 * VOX) + ((zz << 6) + yy) * 64 + xx;
        const float* c1 = c0 + VOX;
        float2 a0 = *(const float2*)c0;          // (y,  x..x+1) ch0
        float2 a1 = *(const float2*)(c0 + 64);   // (y+1,x..x+1) ch0
        float2 d0 = *(const float2*)c1;          // ch1
        float2 d1 = *(const float2*)(c1 + 64);
        vox4[idx] = make_uint4(pk2(a0.x, d0.x), pk2(a0.y, d0.y),
                               pk2(a1.x, d1.x), pk2(a1.y, d1.y));
    } else if (b < PREP_VB + PREP_CB) {
        // per-point cell id + global histogram
        int p = (b - PREP_VB) * 256 + tid;
        int c = cell_of(x[p * 3 + 0], x[p * 3 + 1], x[p * 3 + 2]);
        cid[p] = (unsigned short)c;
        atomicAdd(&hist[c], 1);
    } else {
        // weights transpose to bf16
        int t = (b - PREP_VB - PREP_CB) * 256 + tid;   // 0..4095
        for (int i = t; i < NODES * K0; i += 4096) {
            int n = i / K0, k = i - n * K0;
            w0t[i] = (k < 164) ? f2bf(W0[k * NODES + n]) : (unsigned short)0;
        }
        for (int i = t; i < NODES * NODES; i += 4096) {
            int n = i >> 6, k = i & 63;
            w1t[i] = f2bf(W1[k * NODES + n]);
        }
    }
}

// ---- sort 2: exclusive scan of 4096 bins (1 block, 256 threads x 16 bins) ----
__global__ void sort_scan(const int* __restrict__ hist, int* __restrict__ offs) {
    __shared__ int partial[256];
    int t = threadIdx.x;
    int loc[16];
    int s = 0;
    #pragma unroll
    for (int i = 0; i < 16; ++i) { loc[i] = s; s += hist[t * 16 + i]; }
    partial[t] = s;
    __syncthreads();
    for (int d = 1; d < 256; d <<= 1) {
        int v = (t >= d) ? partial[t - d] : 0;
        __syncthreads();
        partial[t] += v;
        __syncthreads();
    }
    int base = partial[t] - s;      // exclusive
    #pragma unroll
    for (int i = 0; i < 16; ++i) offs[t * 16 + i] = base + loc[i];
}

// ---- sort 3: scatter points to sorted order (destroys offs) ----
__global__ void sort_scatter(const float* __restrict__ x, const unsigned short* __restrict__ cell_id,
                             int* __restrict__ offs, float4* __restrict__ spts) {
    int p = blockIdx.x * blockDim.x + threadIdx.x;
    int c = cell_id[p];
    int pos = atomicAdd(&offs[c], 1);
    spts[pos] = make_float4(x[p * 3 + 0], x[p * 3 + 1], x[p * 3 + 2], __int_as_float(p));
}

// ---- gather one (pt, g) pair -> packed feature in Fsh (bricked vox) ----
__device__ inline void gather_pair(int pt, int g,
                                   const unsigned int* __restrict__ vox,
                                   const float* xs, const float* gss, const float* gts,
                                   unsigned short* Fsh) {
    float px = xs[pt * 3 + 0], py = xs[pt * 3 + 1], pz = xs[pt * 3 + 2];
    float ix = (px * gss[g * 3 + 0] + gts[g * 3 + 0] + 1.0f) * 31.5f;
    float iy = (py * gss[g * 3 + 1] + gts[g * 3 + 1] + 1.0f) * 31.5f;
    float iz = (pz * gss[g * 3 + 2] + gts[g * 3 + 2] + 1.0f) * 31.5f;
    float fx = floorf(ix), fy = floorf(iy), fz = floorf(iz);
    int x0 = (int)fx, y0 = (int)fy, z0 = (int)fz;
    float wx = ix - fx, wy = iy - fy, wz = iz - fz;
    float wxa0 = (x0 >= 0) ? (1.0f - wx) : 0.0f;
    float wxa1 = (x0 < 63) ? wx : 0.0f;
    float wya0 = (y0 >= 0) ? (1.0f - wy) : 0.0f;
    float wya1 = (y0 < 63) ? wy : 0.0f;
    float wza0 = (z0 >= 0) ? (1.0f - wz) : 0.0f;
    float wza1 = (z0 < 63) ? wz : 0.0f;
    int xc0 = max(x0, 0), xc1 = min(x0 + 1, 63);
    int yc0 = max(y0, 0), yc1 = min(y0 + 1, 63);
    int zc0 = max(z0, 0), zc1 = min(z0 + 1, 63);
    // brick-layout per-axis address parts
    int xp0 = ((xc0 >> 1) << 3) | (xc0 & 1);
    int xp1 = ((xc1 >> 1) << 3) | (xc1 & 1);
    int yp0 = ((yc0 >> 1) << 8) | ((yc0 & 1) << 1);
    int yp1 = ((yc1 >> 1) << 8) | ((yc1 & 1) << 1);
    int zp0 = ((zc0 >> 1) << 13) | ((zc0 & 1) << 2);
    int zp1 = ((zc1 >> 1) << 13) | ((zc1 & 1) << 2);
    const unsigned int* vg = vox + ((size_t)g << 18);
    float f0 = 0.f, f1 = 0.f;
    #pragma unroll
    for (int dz = 0; dz < 2; ++dz) {
        int zp = dz ? zp1 : zp0; float wzv = dz ? wza1 : wza0;
        #pragma unroll
        for (int dy = 0; dy < 2; ++dy) {
            int rowb = zp + (dy ? yp1 : yp0);
            float wzy = wzv * (dy ? wya1 : wya0);
            unsigned int v0 = vg[rowb + xp0], v1 = vg[rowb + xp1];
            f0 += wzy * (wxa0 * bflo(v0) + wxa1 * bflo(v1));
            f1 += wzy * (wxa0 * bfhi(v0) + wxa1 * bfhi(v1));
        }
    }
    *(unsigned int*)&Fsh[pt * SF + 36 + 2 * g] = pk2(f0, f1);
}

// ---- main fused kernel (sorted points, indirect output) ----
__global__ void __launch_bounds__(256, 5)
amrsrn_main(const float4* __restrict__ spts,
            const float* __restrict__ gscale,
            const float* __restrict__ gtrans,
            const unsigned int* __restrict__ vox,
            const unsigned short* __restrict__ w0t,
            const unsigned short* __restrict__ w1t,
            const float* __restrict__ b0,
            const float* __restrict__ b1,
            const float* __restrict__ W2,
            const float* __restrict__ b2,
            float* __restrict__ out) {
    __shared__ unsigned short Fsh[TILE * SF];   // 25600 B
    __shared__ unsigned short wl[WLCAP];        // 4096 B
    __shared__ float xs[TILE * 3];
    __shared__ int   sidx[TILE];
    __shared__ float gss[NG * 3];
    __shared__ float gts[NG * 3];
    __shared__ int wl_cnt;

    const int tid = threadIdx.x;
    const int lane = tid & 63;
    // XCD swizzle: round-robin dispatch -> each XCD gets a contiguous Morton range
    const int cb = ((blockIdx.x & 7) << 10) | (blockIdx.x >> 3);
    const int base = cb * TILE;

    // ---- phase 0: zero F, stage points + tables ----
    for (int i = tid; i < TILE * SF / 8; i += 256) ((uint4*)Fsh)[i] = make_uint4(0,0,0,0);
    if (tid < TILE) {
        float4 sp = spts[base + tid];
        xs[tid * 3 + 0] = sp.x; xs[tid * 3 + 1] = sp.y; xs[tid * 3 + 2] = sp.z;
        sidx[tid] = __float_as_int(sp.w);
    }
    if (tid < NG * 3) { gss[tid] = gscale[tid]; gts[tid] = gtrans[tid]; }
    if (tid == 0) wl_cnt = 0;
    __syncthreads();

    // ---- phase 1a: positional encoding (cols 0..35) ----
    {
        int pt = tid & 63;
        int grp = tid >> 6;
        #pragma unroll
        for (int t = 0; t < 9; ++t) {
            int tau = grp * 9 + t;
            int tt = (tau < 18) ? tau : tau - 18;
            int l = tt / 3, d = tt - l * 3;
            float ang = xs[pt * 3 + d] * (3.14159265358979323846f * (float)(1 << l));
            float val = (tau < 18) ? __sinf(ang) : __cosf(ang);
            Fsh[pt * SF + tau] = f2bf(val);
        }
    }

    // ---- phase 1b: scan 64x64 pairs -> worklist ----
    {
        int pt = tid & 63;
        int gbase = (tid >> 6) * 16;
        float px = xs[pt * 3 + 0], py = xs[pt * 3 + 1], pz = xs[pt * 3 + 2];
        for (int gi = 0; gi < 16; ++gi) {
            int g = gbase + gi;
            float ix = (px * gss[g * 3 + 0] + gts[g * 3 + 0] + 1.0f) * 31.5f;
            float iy = (py * gss[g * 3 + 1] + gts[g * 3 + 1] + 1.0f) * 31.5f;
            float iz = (pz * gss[g * 3 + 2] + gts[g * 3 + 2] + 1.0f) * 31.5f;
            bool valid = (ix >= -1.0f) & (ix < 64.0f)
                       & (iy >= -1.0f) & (iy < 64.0f)
                       & (iz >= -1.0f) & (iz < 64.0f);
            unsigned long long m = __ballot(valid);
            if (m) {
                int b = 0;
                if (lane == 0) b = atomicAdd(&wl_cnt, __popcll(m));
                b = __shfl(b, 0);
                if (valid) {
                    int slot = b + __popcll(m & ((1ull << lane) - 1ull));
                    if (slot < WLCAP) wl[slot] = (unsigned short)((pt << 6) | g);
                    else gather_pair(pt, g, vox, xs, gss, gts, Fsh);
                }
            }
        }
    }
    __syncthreads();

    // ---- phase 2: process worklist ----
    {
        int n = min(wl_cnt, WLCAP);
        for (int i = tid; i < n; i += 256) {
            int e = wl[i];
            gather_pair(e >> 6, e & 63, vox, xs, gss, gts, Fsh);
        }
    }
    __syncthreads();

    // ---- phase 3: MFMA MLP. wave w owns pts [16w, 16w+16) ----
    const int wv = tid >> 6;
    const int ptb = wv * 16;
    const int row = lane & 15;
    const int quad = lane >> 4;
    const int koff = quad * 8;

    f32x4 acc0[4] = {{0,0,0,0},{0,0,0,0},{0,0,0,0},{0,0,0,0}};
    #pragma unroll
    for (int ks = 0; ks < 6; ++ks) {
        bf16x8 a = *(const bf16x8*)&Fsh[(ptb + row) * SF + ks * 32 + koff];
        #pragma unroll
        for (int nt = 0; nt < 4; ++nt) {
            bf16x8 b = *(const bf16x8*)&w0t[(nt * 16 + row) * K0 + ks * 32 + koff];
            acc0[nt] = __builtin_amdgcn_mfma_f32_16x16x32_bf16(a, b, acc0[nt], 0, 0, 0);
        }
    }
    #pragma unroll
    for (int nt = 0; nt < 4; ++nt) {
        int node = nt * 16 + row;
        float bb = b0[node];
        #pragma unroll
        for (int r = 0; r < 4; ++r) {
            float h = acc0[nt][r] + bb;
            float s = __sinf(h);
            h = 0.5f * h + s * s;
            Fsh[(ptb + quad * 4 + r) * SF + node] = f2bf(h);
        }
    }

    f32x4 acc1[4] = {{0,0,0,0},{0,0,0,0},{0,0,0,0},{0,0,0,0}};
    #pragma unroll
    for (int ks = 0; ks < 2; ++ks) {
        bf16x8 a = *(const bf16x8*)&Fsh[(ptb + row) * SF + ks * 32 + koff];
        #pragma unroll
        for (int nt = 0; nt < 4; ++nt) {
            bf16x8 b = *(const bf16x8*)&w1t[(nt * 16 + row) * NODES + ks * 32 + koff];
            acc1[nt] = __builtin_amdgcn_mfma_f32_16x16x32_bf16(a, b, acc1[nt], 0, 0, 0);
        }
    }
    float part[4] = {0.f, 0.f, 0.f, 0.f};
    #pragma unroll
    for (int nt = 0; nt < 4; ++nt) {
        int node = nt * 16 + row;
        float b1v = b1[node];
        float w2v = W2[node];
        #pragma unroll
        for (int r = 0; r < 4; ++r) {
            float h = acc1[nt][r] + b1v;
            float s = __sinf(h);
            h = 0.5f * h + s * s;
            part[r] += h * w2v;
        }
    }
    #pragma unroll
    for (int m = 1; m < 16; m <<= 1) {
        #pragma unroll
        for (int r = 0; r < 4; ++r) part[r] += __shfl_xor(part[r], m);
    }
    if (row == 0) {
        float b2v = b2[0];
        #pragma unroll
        for (int r = 0; r < 4; ++r) {
            int pt = ptb + quad * 4 + r;
            out[sidx[pt]] = part[r] + b2v;
        }
    }
}

// ---- fallback (no workspace): direct fp32 kernel ----
__global__ void amrsrn_fallback(const float* __restrict__ x,
                                const float* __restrict__ gscale,
                                const float* __restrict__ gtrans,
                                const float* __restrict__ fg,
                                const float* __restrict__ W0,
                                const float* __restrict__ b0,
                                const float* __restrict__ W1,
                                const float* __restrict__ b1,
                                const float* __restrict__ W2,
                                const float* __restrict__ b2,
                                float* __restrict__ out) {
    int p = blockIdx.x * blockDim.x + threadIdx.x;
    float px = x[p*3+0], py = x[p*3+1], pz = x[p*3+2];
    float h0[NODES];
    #pragma unroll
    for (int j = 0; j < NODES; ++j) h0[j] = b0[j];
    #pragma unroll
    for (int l = 0; l < 6; ++l) {
        float freq = 3.14159265358979323846f * (float)(1 << l);
        #pragma unroll
        for (int d = 0; d < 3; ++d) {
            float v = (d == 0 ? px : (d == 1 ? py : pz)) * freq;
            float s = __sinf(v), c = __cosf(v);
            const float* wrs = W0 + (l*3 + d) * NODES;
            const float* wrc = W0 + (18 + l*3 + d) * NODES;
            #pragma unroll
            for (int j = 0; j < NODES; ++j) h0[j] += s * wrs[j] + c * wrc[j];
        }
    }
    for (int g = 0; g < NG; ++g) {
        float ix = (px * gscale[g*3+0] + gtrans[g*3+0] + 1.0f) * 31.5f;
        float iy = (py * gscale[g*3+1] + gtrans[g*3+1] + 1.0f) * 31.5f;
        float iz = (pz * gscale[g*3+2] + gtrans[g*3+2] + 1.0f) * 31.5f;
        float fxf = floorf(ix), fyf = floorf(iy), fzf = floorf(iz);
        int x0 = (int)fxf, y0 = (int)fyf, z0 = (int)fzf;
        float wx = ix - fxf, wy = iy - fyf, wz = iz - fzf;
        bool any = (x0 >= -1 && x0 < GSZ) && (y0 >= -1 && y0 < GSZ) && (z0 >= -1 && z0 < GSZ);
        if (any) {
            float f0 = 0.f, f1 = 0.f;
            #pragma unroll
            for (int dz = 0; dz < 2; ++dz) {
                int zi = z0 + dz; bool vz = ((unsigned)zi < (unsigned)GSZ);
                int zc = min(max(zi, 0), GSZ - 1);
                float wzf = dz ? wz : 1.f - wz;
                #pragma unroll
                for (int dy = 0; dy < 2; ++dy) {
                    int yi = y0 + dy; bool vy = ((unsigned)yi < (unsigned)GSZ);
                    int yc = min(max(yi, 0), GSZ - 1);
                    float wyf = dy ? wy : 1.f - wy;
                    int rowoff = (zc * GSZ + yc) * GSZ;
                    #pragma unroll
                    for (int dx = 0; dx < 2; ++dx) {
                        int xi = x0 + dx; bool vx = ((unsigned)xi < (unsigned)GSZ);
                        int xc = min(max(xi, 0), GSZ - 1);
                        float w = wzf * wyf * (dx ? wx : 1.f - wx);
                        w = (vz && vy && vx) ? w : 0.f;
                        const float* gp = fg + ((size_t)g << 19);
                        f0 += w * gp[rowoff + xc];
                        f1 += w * gp[VOX + rowoff + xc];
                    }
                }
            }
            const float* wr = W0 + (36 + 2*g) * NODES;
            #pragma unroll
            for (int j = 0; j < NODES; ++j) h0[j] += f0 * wr[j] + f1 * wr[NODES + j];
        }
    }
    #pragma unroll
    for (int j = 0; j < NODES; ++j) { float s = __sinf(h0[j]); h0[j] = 0.5f * h0[j] + s * s; }
    float out_acc = b2[0];
    #pragma unroll
    for (int half = 0; half < 2; ++half) {
        float h1[32];
        #pragma unroll
        for (int j = 0; j < 32; ++j) h1[j] = b1[half*32 + j];
        #pragma unroll
        for (int i = 0; i < NODES; ++i) {
            float a = h0[i];
            const float* w1r = W1 + i * NODES + half*32;
            #pragma unroll
            for (int j = 0; j < 32; ++j) h1[j] += a * w1r[j];
        }
        #pragma unroll
        for (int j = 0; j < 32; ++j) { float s = __sinf(h1[j]); out_acc += (0.5f * h1[j] + s * s) * W2[half*32 + j]; }
    }
    out[p] = out_acc;
}

extern "C" void kernel_launch(void* const* d_in, const int* in_sizes, int n_in,
                              void* d_out, int out_size, void* d_ws, size_t ws_size,
                              hipStream_t stream) {
    const float* x      = (const float*)d_in[0];
    const float* gscale = (const float*)d_in[1];
    const float* gtrans = (const float*)d_in[2];
    const float* fg     = (const float*)d_in[3];
    const float* W0     = (const float*)d_in[4];
    const float* b0     = (const float*)d_in[5];
    const float* W1     = (const float*)d_in[6];
    const float* b1     = (const float*)d_in[7];
    const float* W2     = (const float*)d_in[8];
    const float* b2     = (const float*)d_in[9];
    float* out = (float*)d_out;

    // workspace layout (all within 128 MiB):
    //   [0,       24576)  w0t
    //   [24576,   32768)  w1t
    //   [64K,     80K)    hist (4096 int)
    //   [80K,     96K)    offs (4096 int)
    //   [96K,     96K+1M) cell_id (524288 u16)
    //   [+,       +8M)    sorted pts (524288 float4)
    //   [+,       +64M)   vox (bricked)
    char* wsp = (char*)d_ws;
    unsigned short* w0t = (unsigned short*)wsp;
    unsigned short* w1t = w0t + NODES * K0;
    int* hist           = (int*)(wsp + (64 << 10));
    int* offs           = (int*)(wsp + (80 << 10));
    unsigned short* cid = (unsigned short*)(wsp + (96 << 10));
    float4* spts        = (float4*)(wsp + (96 << 10) + (1 << 20));
    unsigned int* vox   = (unsigned int*)(wsp + (96 << 10) + (1 << 20) + (8 << 20));
    const size_t ws_needed = (96 << 10) + (1 << 20) + (8 << 20) + (size_t)NG * VOX * 4;

    if (ws_size >= ws_needed) {
        hipMemsetAsync(hist, 0, NCELL * sizeof(int), stream);
        prep_fused<<<PREP_VB + PREP_CB + 16, 256, 0, stream>>>(
            fg, (uint4*)vox, x, cid, hist, W0, W1, w0t, w1t);
        sort_scan<<<1, 256, 0, stream>>>(hist, offs);
        sort_scatter<<<NPTS / 256, 256, 0, stream>>>(x, cid, offs, spts);
        amrsrn_main<<<NBLK, 256, 0, stream>>>(spts, gscale, gtrans, vox,
                                              w0t, w1t, b0, b1, W2, b2, out);
    } else {
        amrsrn_fallback<<<NPTS / 256, 256, 0, stream>>>(
            x, gscale, gtrans, fg, W0, b0, W1, b1, W2, b2, out);
    }
}

// Round 3
// 448.413 us; speedup vs baseline: 1.1133x; 1.0021x over previous
//
#include <hip/hip_runtime.h>
#include <hip/hip_bf16.h>

#define NPTS    524288
#define NG      64
#define GSZ     64
#define VOX     (GSZ*GSZ*GSZ)       // 262144
#define NODES   64
#define TILE    64                  // points per block
#define NBLK    (NPTS / TILE)       // 8192
#define K0      192                 // padded K for layer-0 (164 -> 192)
#define SF      200                 // Fsh row stride (bf16) - natural bank stagger
#define NCELL   4096                // 16^3 Morton cells
#define PREP_VB 16384               // vox-repack blocks in prep_fused
#define PREP_CB 2048                // sort-count blocks in prep_fused

typedef __attribute__((ext_vector_type(8))) short bf16x8;
typedef __attribute__((ext_vector_type(4))) float f32x4;

__device__ inline unsigned short f2bf(float f) {
    __hip_bfloat16 b = __float2bfloat16(f);
    union { __hip_bfloat16 h; unsigned short u; } cv; cv.h = b;
    return cv.u;
}
__device__ inline unsigned int pk2(float c0, float c1) {
    return (unsigned int)f2bf(c0) | ((unsigned int)f2bf(c1) << 16);
}
__device__ inline float bflo(unsigned int v) { return __uint_as_float(v << 16); }
__device__ inline float bfhi(unsigned int v) { return __uint_as_float(v & 0xffff0000u); }

__device__ inline int spread4(int v) {   // 4 bits -> bits 0,3,6,9
    return (v & 1) | ((v & 2) << 2) | ((v & 4) << 4) | ((v & 8) << 6);
}
__device__ inline int cell_of(float px, float py, float pz) {
    int cx = min(max((int)((px + 1.0f) * 8.0f), 0), 15);
    int cy = min(max((int)((py + 1.0f) * 8.0f), 0), 15);
    int cz = min(max((int)((pz + 1.0f) * 8.0f), 0), 15);
    return spread4(cx) | (spread4(cy) << 1) | (spread4(cz) << 2);
}

// Bricked vox layout: 2x2x2-voxel bricks (8 u32 = 32B), bricks linear in
// (bz,by,bx).  idx = (bz<<13 | by<<8 | bx<<3) + (lz<<2 | ly<<1 | lx).
// A 128B cache line covers an 8x2x2 voxel region (vs 32x1x1 for linear).

// ---- fused prep: vox brick-repack + sort histogram + weight prep ----
// hist must be zeroed (hipMemsetAsync) before this kernel.
__global__ void prep_fused(const float* __restrict__ fg, uint4* __restrict__ vox4,
                           const float* __restrict__ x, unsigned short* __restrict__ cid,
                           int* __restrict__ hist,
                           const float* __restrict__ W0, const float* __restrict__ W1,
                           unsigned short* __restrict__ w0t, unsigned short* __restrict__ w1t) {
    int b = blockIdx.x;
    int tid = threadIdx.x;
    if (b < PREP_VB) {
        // each thread writes one uint4 = half-brick (fixed lz), coalesced out
        int idx = b * 256 + tid;            // NG * VOX/4 total
        int g = idx >> 16;                   // 65536 half-bricks per grid
        int hb = idx & 65535;
        int brick = hb >> 1;
        int h = hb & 1;                      // lz
        int bx = brick & 31, by = (brick >> 5) & 31, bz = brick >> 10;
        int xx = bx << 1, yy = by << 1, zz = (bz << 1) + h;
        const float* c0 = fg + (size_t)g * (2 * VOX) + ((zz << 6) + yy) * 64 + xx;
        const float* c1 = c0 + VOX;
        float2 a0 = *(const float2*)c0;          // (y,  x..x+1) ch0
        float2 a1 = *(const float2*)(c0 + 64);   // (y+1,x..x+1) ch0
        float2 d0 = *(const float2*)c1;          // ch1
        float2 d1 = *(const float2*)(c1 + 64);
        vox4[idx] = make_uint4(pk2(a0.x, d0.x), pk2(a0.y, d0.y),
                               pk2(a1.x, d1.x), pk2(a1.y, d1.y));
    } else if (b < PREP_VB + PREP_CB) {
        // per-point cell id + global histogram
        int p = (b - PREP_VB) * 256 + tid;
        int c = cell_of(x[p * 3 + 0], x[p * 3 + 1], x[p * 3 + 2]);
        cid[p] = (unsigned short)c;
        atomicAdd(&hist[c], 1);
    } else {
        // weights transpose to bf16
        int t = (b - PREP_VB - PREP_CB) * 256 + tid;   // 0..4095
        for (int i = t; i < NODES * K0; i += 4096) {
            int n = i / K0, k = i - n * K0;
            w0t[i] = (k < 164) ? f2bf(W0[k * NODES + n]) : (unsigned short)0;
        }
        for (int i = t; i < NODES * NODES; i += 4096) {
            int n = i >> 6, k = i & 63;
            w1t[i] = f2bf(W1[k * NODES + n]);
        }
    }
}

// ---- sort 2: exclusive scan of 4096 bins (1 block, 256 threads x 16 bins) ----
__global__ void sort_scan(const int* __restrict__ hist, int* __restrict__ offs) {
    __shared__ int partial[256];
    int t = threadIdx.x;
    int loc[16];
    int s = 0;
    #pragma unroll
    for (int i = 0; i < 16; ++i) { loc[i] = s; s += hist[t * 16 + i]; }
    partial[t] = s;
    __syncthreads();
    for (int d = 1; d < 256; d <<= 1) {
        int v = (t >= d) ? partial[t - d] : 0;
        __syncthreads();
        partial[t] += v;
        __syncthreads();
    }
    int base = partial[t] - s;      // exclusive
    #pragma unroll
    for (int i = 0; i < 16; ++i) offs[t * 16 + i] = base + loc[i];
}

// ---- sort 3: scatter points to sorted order (destroys offs) ----
__global__ void sort_scatter(const float* __restrict__ x, const unsigned short* __restrict__ cell_id,
                             int* __restrict__ offs, float4* __restrict__ spts) {
    int p = blockIdx.x * blockDim.x + threadIdx.x;
    int c = cell_id[p];
    int pos = atomicAdd(&offs[c], 1);
    spts[pos] = make_float4(x[p * 3 + 0], x[p * 3 + 1], x[p * 3 + 2], __int_as_float(p));
}

// ---- gather one (pt, g) pair -> packed feature in Fsh (bricked vox) ----
// requires ix,iy,iz in [-1, 64) (guaranteed by caller's valid test / full-mask)
__device__ inline void gather_pair(int pt, int g, float ix, float iy, float iz,
                                   const unsigned int* __restrict__ vox,
                                   unsigned short* Fsh) {
    float fx = floorf(ix), fy = floorf(iy), fz = floorf(iz);
    int x0 = (int)fx, y0 = (int)fy, z0 = (int)fz;
    float wx = ix - fx, wy = iy - fy, wz = iz - fz;
    float wxa0 = (x0 >= 0) ? (1.0f - wx) : 0.0f;
    float wxa1 = (x0 < 63) ? wx : 0.0f;
    float wya0 = (y0 >= 0) ? (1.0f - wy) : 0.0f;
    float wya1 = (y0 < 63) ? wy : 0.0f;
    float wza0 = (z0 >= 0) ? (1.0f - wz) : 0.0f;
    float wza1 = (z0 < 63) ? wz : 0.0f;
    int xc0 = max(x0, 0), xc1 = min(x0 + 1, 63);
    int yc0 = max(y0, 0), yc1 = min(y0 + 1, 63);
    int zc0 = max(z0, 0), zc1 = min(z0 + 1, 63);
    // brick-layout per-axis address parts
    int xp0 = ((xc0 >> 1) << 3) | (xc0 & 1);
    int xp1 = ((xc1 >> 1) << 3) | (xc1 & 1);
    int yp0 = ((yc0 >> 1) << 8) | ((yc0 & 1) << 1);
    int yp1 = ((yc1 >> 1) << 8) | ((yc1 & 1) << 1);
    int zp0 = ((zc0 >> 1) << 13) | ((zc0 & 1) << 2);
    int zp1 = ((zc1 >> 1) << 13) | ((zc1 & 1) << 2);
    const unsigned int* vg = vox + ((size_t)g << 18);
    float f0 = 0.f, f1 = 0.f;
    #pragma unroll
    for (int dz = 0; dz < 2; ++dz) {
        int zp = dz ? zp1 : zp0; float wzv = dz ? wza1 : wza0;
        #pragma unroll
        for (int dy = 0; dy < 2; ++dy) {
            int rowb = zp + (dy ? yp1 : yp0);
            float wzy = wzv * (dy ? wya1 : wya0);
            unsigned int v0 = vg[rowb + xp0], v1 = vg[rowb + xp1];
            f0 += wzy * (wxa0 * bflo(v0) + wxa1 * bflo(v1));
            f1 += wzy * (wxa0 * bfhi(v0) + wxa1 * bfhi(v1));
        }
    }
    *(unsigned int*)&Fsh[pt * SF + 36 + 2 * g] = pk2(f0, f1);
}

// ---- main fused kernel (sorted points, indirect output) ----
// Block-AABB grid classification: mfull (all 64 pts valid) gathered directly,
// mpart (boundary) gets the exact per-point test, rest skipped entirely.
__global__ void __launch_bounds__(256, 5)
amrsrn_main(const float4* __restrict__ spts,
            const float* __restrict__ gscale,
            const float* __restrict__ gtrans,
            const unsigned int* __restrict__ vox,
            const unsigned short* __restrict__ w0t,
            const unsigned short* __restrict__ w1t,
            const float* __restrict__ b0,
            const float* __restrict__ b1,
            const float* __restrict__ W2,
            const float* __restrict__ b2,
            float* __restrict__ out) {
    __shared__ unsigned short Fsh[TILE * SF];   // 25600 B
    __shared__ int   sidx[TILE];
    __shared__ float gss[NG * 3];
    __shared__ float gts[NG * 3];

    const int tid = threadIdx.x;
    const int lane = tid & 63;
    const int wv = tid >> 6;
    // XCD swizzle: round-robin dispatch -> each XCD gets a contiguous Morton range
    const int cb = ((blockIdx.x & 7) << 10) | (blockIdx.x >> 3);
    const int base = cb * TILE;

    // ---- phase 0: zero F, stage tables; every thread holds its own point ----
    for (int i = tid; i < TILE * SF / 8; i += 256) ((uint4*)Fsh)[i] = make_uint4(0,0,0,0);
    float4 sp = spts[base + lane];          // all 4 waves load same 64 pts (L1)
    const float px = sp.x, py = sp.y, pz = sp.z;
    if (tid < TILE) sidx[tid] = __float_as_int(sp.w);
    if (tid < NG * 3) { gss[tid] = gscale[tid]; gts[tid] = gtrans[tid]; }
    __syncthreads();

    // ---- phase 1a: block AABB + per-grid classification (each wave redundantly) ----
    float lox = px, hix = px, loy = py, hiy = py, loz = pz, hiz = pz;
    #pragma unroll
    for (int m = 1; m < 64; m <<= 1) {
        lox = fminf(lox, __shfl_xor(lox, m)); hix = fmaxf(hix, __shfl_xor(hix, m));
        loy = fminf(loy, __shfl_xor(loy, m)); hiy = fmaxf(hiy, __shfl_xor(hiy, m));
        loz = fminf(loz, __shfl_xor(loz, m)); hiz = fmaxf(hiz, __shfl_xor(hiz, m));
    }
    unsigned long long mfull, mpart;
    {
        int g = lane;                       // lane <-> grid
        float s0 = gss[g*3+0], s1 = gss[g*3+1], s2 = gss[g*3+2];
        float t0 = gts[g*3+0], t1 = gts[g*3+1], t2 = gts[g*3+2];
        // transforms are monotone in p (scales >= 1 > 0)
        float xl = (lox*s0 + t0 + 1.0f)*31.5f, xh = (hix*s0 + t0 + 1.0f)*31.5f;
        float yl = (loy*s1 + t1 + 1.0f)*31.5f, yh = (hiy*s1 + t1 + 1.0f)*31.5f;
        float zl = (loz*s2 + t2 + 1.0f)*31.5f, zh = (hiz*s2 + t2 + 1.0f)*31.5f;
        // margins (1e-3 >> few-ulp cross-site arithmetic differences) keep
        // full conservative-safe; out conservative the other way; partial
        // runs the exact per-point test so semantics are bit-identical.
        bool fullg = (xl >= -0.999f) & (xh <= 63.999f)
                   & (yl >= -0.999f) & (yh <= 63.999f)
                   & (zl >= -0.999f) & (zh <= 63.999f);
        bool outg  = (xh < -1.001f) | (xl >= 64.001f)
                   | (yh < -1.001f) | (yl >= 64.001f)
                   | (zh < -1.001f) | (zl >= 64.001f);
        mfull = __ballot(fullg);
        mpart = __ballot(!fullg && !outg);
    }

    // ---- phase 1b: positional encoding (cols 0..35) ----
    {
        #pragma unroll
        for (int t = 0; t < 9; ++t) {
            int tau = wv * 9 + t;
            int tt = (tau < 18) ? tau : tau - 18;
            int l = tt / 3, d = tt - l * 3;
            float c = (d == 0) ? px : ((d == 1) ? py : pz);
            float ang = c * (3.14159265358979323846f * (float)(1 << l));
            float val = (tau < 18) ? __sinf(ang) : __cosf(ang);
            Fsh[lane * SF + tau] = f2bf(val);
        }
    }

    // ---- phase 1c: gathers. round-robin full+partial grids across waves ----
    {
        int idx = 0;
        unsigned long long m = mfull;
        while (m) {
            int g = __builtin_ctzll(m);
            m &= m - 1;
            if ((idx++ & 3) == wv) {
                float ix = (px * gss[g*3+0] + gts[g*3+0] + 1.0f) * 31.5f;
                float iy = (py * gss[g*3+1] + gts[g*3+1] + 1.0f) * 31.5f;
                float iz = (pz * gss[g*3+2] + gts[g*3+2] + 1.0f) * 31.5f;
                gather_pair(lane, g, ix, iy, iz, vox, Fsh);
            }
        }
        m = mpart;
        while (m) {
            int g = __builtin_ctzll(m);
            m &= m - 1;
            if ((idx++ & 3) == wv) {
                float ix = (px * gss[g*3+0] + gts[g*3+0] + 1.0f) * 31.5f;
                float iy = (py * gss[g*3+1] + gts[g*3+1] + 1.0f) * 31.5f;
                float iz = (pz * gss[g*3+2] + gts[g*3+2] + 1.0f) * 31.5f;
                bool valid = (ix >= -1.0f) & (ix < 64.0f)
                           & (iy >= -1.0f) & (iy < 64.0f)
                           & (iz >= -1.0f) & (iz < 64.0f);
                if (valid) gather_pair(lane, g, ix, iy, iz, vox, Fsh);
            }
        }
    }
    __syncthreads();

    // ---- phase 2: MFMA MLP. wave w owns pts [16w, 16w+16) ----
    const int ptb = wv * 16;
    const int row = lane & 15;
    const int quad = lane >> 4;
    const int koff = quad * 8;

    f32x4 acc0[4] = {{0,0,0,0},{0,0,0,0},{0,0,0,0},{0,0,0,0}};
    #pragma unroll
    for (int ks = 0; ks < 6; ++ks) {
        bf16x8 a = *(const bf16x8*)&Fsh[(ptb + row) * SF + ks * 32 + koff];
        #pragma unroll
        for (int nt = 0; nt < 4; ++nt) {
            bf16x8 b = *(const bf16x8*)&w0t[(nt * 16 + row) * K0 + ks * 32 + koff];
            acc0[nt] = __builtin_amdgcn_mfma_f32_16x16x32_bf16(a, b, acc0[nt], 0, 0, 0);
        }
    }
    #pragma unroll
    for (int nt = 0; nt < 4; ++nt) {
        int node = nt * 16 + row;
        float bb = b0[node];
        #pragma unroll
        for (int r = 0; r < 4; ++r) {
            float h = acc0[nt][r] + bb;
            float s = __sinf(h);
            h = 0.5f * h + s * s;
            Fsh[(ptb + quad * 4 + r) * SF + node] = f2bf(h);
        }
    }

    f32x4 acc1[4] = {{0,0,0,0},{0,0,0,0},{0,0,0,0},{0,0,0,0}};
    #pragma unroll
    for (int ks = 0; ks < 2; ++ks) {
        bf16x8 a = *(const bf16x8*)&Fsh[(ptb + row) * SF + ks * 32 + koff];
        #pragma unroll
        for (int nt = 0; nt < 4; ++nt) {
            bf16x8 b = *(const bf16x8*)&w1t[(nt * 16 + row) * NODES + ks * 32 + koff];
            acc1[nt] = __builtin_amdgcn_mfma_f32_16x16x32_bf16(a, b, acc1[nt], 0, 0, 0);
        }
    }
    float part[4] = {0.f, 0.f, 0.f, 0.f};
    #pragma unroll
    for (int nt = 0; nt < 4; ++nt) {
        int node = nt * 16 + row;
        float b1v = b1[node];
        float w2v = W2[node];
        #pragma unroll
        for (int r = 0; r < 4; ++r) {
            float h = acc1[nt][r] + b1v;
            float s = __sinf(h);
            h = 0.5f * h + s * s;
            part[r] += h * w2v;
        }
    }
    #pragma unroll
    for (int m = 1; m < 16; m <<= 1) {
        #pragma unroll
        for (int r = 0; r < 4; ++r) part[r] += __shfl_xor(part[r], m);
    }
    if (row == 0) {
        float b2v = b2[0];
        #pragma unroll
        for (int r = 0; r < 4; ++r) {
            int pt = ptb + quad * 4 + r;
            out[sidx[pt]] = part[r] + b2v;
        }
    }
}

// ---- fallback (no workspace): direct fp32 kernel ----
__global__ void amrsrn_fallback(const float* __restrict__ x,
                                const float* __restrict__ gscale,
                                const float* __restrict__ gtrans,
                                const float* __restrict__ fg,
                                const float* __restrict__ W0,
                                const float* __restrict__ b0,
                                const float* __restrict__ W1,
                                const float* __restrict__ b1,
                                const float* __restrict__ W2,
                                const float* __restrict__ b2,
                                float* __restrict__ out) {
    int p = blockIdx.x * blockDim.x + threadIdx.x;
    float px = x[p*3+0], py = x[p*3+1], pz = x[p*3+2];
    float h0[NODES];
    #pragma unroll
    for (int j = 0; j < NODES; ++j) h0[j] = b0[j];
    #pragma unroll
    for (int l = 0; l < 6; ++l) {
        float freq = 3.14159265358979323846f * (float)(1 << l);
        #pragma unroll
        for (int d = 0; d < 3; ++d) {
            float v = (d == 0 ? px : (d == 1 ? py : pz)) * freq;
            float s = __sinf(v), c = __cosf(v);
            const float* wrs = W0 + (l*3 + d) * NODES;
            const float* wrc = W0 + (18 + l*3 + d) * NODES;
            #pragma unroll
            for (int j = 0; j < NODES; ++j) h0[j] += s * wrs[j] + c * wrc[j];
        }
    }
    for (int g = 0; g < NG; ++g) {
        float ix = (px * gscale[g*3+0] + gtrans[g*3+0] + 1.0f) * 31.5f;
        float iy = (py * gscale[g*3+1] + gtrans[g*3+1] + 1.0f) * 31.5f;
        float iz = (pz * gscale[g*3+2] + gtrans[g*3+2] + 1.0f) * 31.5f;
        float fxf = floorf(ix), fyf = floorf(iy), fzf = floorf(iz);
        int x0 = (int)fxf, y0 = (int)fyf, z0 = (int)fzf;
        float wx = ix - fxf, wy = iy - fyf, wz = iz - fzf;
        bool any = (x0 >= -1 && x0 < GSZ) && (y0 >= -1 && y0 < GSZ) && (z0 >= -1 && z0 < GSZ);
        if (any) {
            float f0 = 0.f, f1 = 0.f;
            #pragma unroll
            for (int dz = 0; dz < 2; ++dz) {
                int zi = z0 + dz; bool vz = ((unsigned)zi < (unsigned)GSZ);
                int zc = min(max(zi, 0), GSZ - 1);
                float wzf = dz ? wz : 1.f - wz;
                #pragma unroll
                for (int dy = 0; dy < 2; ++dy) {
                    int yi = y0 + dy; bool vy = ((unsigned)yi < (unsigned)GSZ);
                    int yc = min(max(yi, 0), GSZ - 1);
                    float wyf = dy ? wy : 1.f - wy;
                    int rowoff = (zc * GSZ + yc) * GSZ;
                    #pragma unroll
                    for (int dx = 0; dx < 2; ++dx) {
                        int xi = x0 + dx; bool vx = ((unsigned)xi < (unsigned)GSZ);
                        int xc = min(max(xi, 0), GSZ - 1);
                        float w = wzf * wyf * (dx ? wx : 1.f - wx);
                        w = (vz && vy && vx) ? w : 0.f;
                        const float* gp = fg + ((size_t)g << 19);
                        f0 += w * gp[rowoff + xc];
                        f1 += w * gp[VOX + rowoff + xc];
                    }
                }
            }
            const float* wr = W0 + (36 + 2*g) * NODES;
            #pragma unroll
            for (int j = 0; j < NODES; ++j) h0[j] += f0 * wr[j] + f1 * wr[NODES + j];
        }
    }
    #pragma unroll
    for (int j = 0; j < NODES; ++j) { float s = __sinf(h0[j]); h0[j] = 0.5f * h0[j] + s * s; }
    float out_acc = b2[0];
    #pragma unroll
    for (int half = 0; half < 2; ++half) {
        float h1[32];
        #pragma unroll
        for (int j = 0; j < 32; ++j) h1[j] = b1[half*32 + j];
        #pragma unroll
        for (int i = 0; i < NODES; ++i) {
            float a = h0[i];
            const float* w1r = W1 + i * NODES + half*32;
            #pragma unroll
            for (int j = 0; j < 32; ++j) h1[j] += a * w1r[j];
        }
        #pragma unroll
        for (int j = 0; j < 32; ++j) { float s = __sinf(h1[j]); out_acc += (0.5f * h1[j] + s * s) * W2[half*32 + j]; }
    }
    out[p] = out_acc;
}

extern "C" void kernel_launch(void* const* d_in, const int* in_sizes, int n_in,
                              void* d_out, int out_size, void* d_ws, size_t ws_size,
                              hipStream_t stream) {
    const float* x      = (const float*)d_in[0];
    const float* gscale = (const float*)d_in[1];
    const float* gtrans = (const float*)d_in[2];
    const float* fg     = (const float*)d_in[3];
    const float* W0     = (const float*)d_in[4];
    const float* b0     = (const float*)d_in[5];
    const float* W1     = (const float*)d_in[6];
    const float* b1     = (const float*)d_in[7];
    const float* W2     = (const float*)d_in[8];
    const float* b2     = (const float*)d_in[9];
    float* out = (float*)d_out;

    // workspace layout (all within 128 MiB):
    //   [0,       24576)  w0t
    //   [24576,   32768)  w1t
    //   [64K,     80K)    hist (4096 int)
    //   [80K,     96K)    offs (4096 int)
    //   [96K,     96K+1M) cell_id (524288 u16)
    //   [+,       +8M)    sorted pts (524288 float4)
    //   [+,       +64M)   vox (bricked)
    char* wsp = (char*)d_ws;
    unsigned short* w0t = (unsigned short*)wsp;
    unsigned short* w1t = w0t + NODES * K0;
    int* hist           = (int*)(wsp + (64 << 10));
    int* offs           = (int*)(wsp + (80 << 10));
    unsigned short* cid = (unsigned short*)(wsp + (96 << 10));
    float4* spts        = (float4*)(wsp + (96 << 10) + (1 << 20));
    unsigned int* vox   = (unsigned int*)(wsp + (96 << 10) + (1 << 20) + (8 << 20));
    const size_t ws_needed = (96 << 10) + (1 << 20) + (8 << 20) + (size_t)NG * VOX * 4;

    if (ws_size >= ws_needed) {
        hipMemsetAsync(hist, 0, NCELL * sizeof(int), stream);
        prep_fused<<<PREP_VB + PREP_CB + 16, 256, 0, stream>>>(
            fg, (uint4*)vox, x, cid, hist, W0, W1, w0t, w1t);
        sort_scan<<<1, 256, 0, stream>>>(hist, offs);
        sort_scatter<<<NPTS / 256, 256, 0, stream>>>(x, cid, offs, spts);
        amrsrn_main<<<NBLK, 256, 0, stream>>>(spts, gscale, gtrans, vox,
                                              w0t, w1t, b0, b1, W2, b2, out);
    } else {
        amrsrn_fallback<<<NPTS / 256, 256, 0, stream>>>(
            x, gscale, gtrans, fg, W0, b0, W1, b1, W2, b2, out);
    }
}

// Round 4
// 448.144 us; speedup vs baseline: 1.1140x; 1.0006x over previous
//
#include <hip/hip_runtime.h>
#include <hip/hip_bf16.h>

#define NPTS    524288
#define NG      64
#define GSZ     64
#define VOX     (GSZ*GSZ*GSZ)       // 262144
#define NODES   64
#define TILE    64                  // points per block
#define NBLK    (NPTS / TILE)       // 8192
#define K0      192                 // padded K for layer-0 (164 -> 192)
#define SF      200                 // Fsh row stride (bf16) - natural bank stagger
#define NCELL   4096                // 16^3 Morton cells
#define PREP_VB 16384               // vox-repack blocks in prep_fused
#define PREP_CB 2048                // sort-count blocks in prep_fused

typedef __attribute__((ext_vector_type(8))) short bf16x8;
typedef __attribute__((ext_vector_type(4))) float f32x4;

__device__ inline unsigned short f2bf(float f) {
    __hip_bfloat16 b = __float2bfloat16(f);
    union { __hip_bfloat16 h; unsigned short u; } cv; cv.h = b;
    return cv.u;
}
__device__ inline unsigned int pk2(float c0, float c1) {
    return (unsigned int)f2bf(c0) | ((unsigned int)f2bf(c1) << 16);
}
__device__ inline float bflo(unsigned int v) { return __uint_as_float(v << 16); }
__device__ inline float bfhi(unsigned int v) { return __uint_as_float(v & 0xffff0000u); }

__device__ inline int spread4(int v) {   // 4 bits -> bits 0,3,6,9
    return (v & 1) | ((v & 2) << 2) | ((v & 4) << 4) | ((v & 8) << 6);
}
__device__ inline int cell_of(float px, float py, float pz) {
    int cx = min(max((int)((px + 1.0f) * 8.0f), 0), 15);
    int cy = min(max((int)((py + 1.0f) * 8.0f), 0), 15);
    int cz = min(max((int)((pz + 1.0f) * 8.0f), 0), 15);
    return spread4(cx) | (spread4(cy) << 1) | (spread4(cz) << 2);
}

// Bricked vox layout: 2x2x2-voxel bricks (8 u32 = 32B), bricks linear in
// (bz,by,bx).  idx = (bz<<13 | by<<8 | bx<<3) + (lz<<2 | ly<<1 | lx).

// ---- fused prep: vox brick-repack + sort histogram + weight prep ----
__global__ void prep_fused(const float* __restrict__ fg, uint4* __restrict__ vox4,
                           const float* __restrict__ x, unsigned short* __restrict__ cid,
                           int* __restrict__ hist,
                           const float* __restrict__ W0, const float* __restrict__ W1,
                           unsigned short* __restrict__ w0t, unsigned short* __restrict__ w1t) {
    int b = blockIdx.x;
    int tid = threadIdx.x;
    if (b < PREP_VB) {
        int idx = b * 256 + tid;            // NG * VOX/4 total
        int g = idx >> 16;
        int hb = idx & 65535;
        int brick = hb >> 1;
        int h = hb & 1;                      // lz
        int bx = brick & 31, by = (brick >> 5) & 31, bz = brick >> 10;
        int xx = bx << 1, yy = by << 1, zz = (bz << 1) + h;
        const float* c0 = fg + (size_t)g * (2 * VOX) + ((zz << 6) + yy) * 64 + xx;
        const float* c1 = c0 + VOX;
        float2 a0 = *(const float2*)c0;
        float2 a1 = *(const float2*)(c0 + 64);
        float2 d0 = *(const float2*)c1;
        float2 d1 = *(const float2*)(c1 + 64);
        vox4[idx] = make_uint4(pk2(a0.x, d0.x), pk2(a0.y, d0.y),
                               pk2(a1.x, d1.x), pk2(a1.y, d1.y));
    } else if (b < PREP_VB + PREP_CB) {
        int p = (b - PREP_VB) * 256 + tid;
        int c = cell_of(x[p * 3 + 0], x[p * 3 + 1], x[p * 3 + 2]);
        cid[p] = (unsigned short)c;
        atomicAdd(&hist[c], 1);
    } else {
        int t = (b - PREP_VB - PREP_CB) * 256 + tid;   // 0..4095
        for (int i = t; i < NODES * K0; i += 4096) {
            int n = i / K0, k = i - n * K0;
            w0t[i] = (k < 164) ? f2bf(W0[k * NODES + n]) : (unsigned short)0;
        }
        for (int i = t; i < NODES * NODES; i += 4096) {
            int n = i >> 6, k = i & 63;
            w1t[i] = f2bf(W1[k * NODES + n]);
        }
    }
}

// ---- sort 2: exclusive scan of 4096 bins ----
__global__ void sort_scan(const int* __restrict__ hist, int* __restrict__ offs) {
    __shared__ int partial[256];
    int t = threadIdx.x;
    int loc[16];
    int s = 0;
    #pragma unroll
    for (int i = 0; i < 16; ++i) { loc[i] = s; s += hist[t * 16 + i]; }
    partial[t] = s;
    __syncthreads();
    for (int d = 1; d < 256; d <<= 1) {
        int v = (t >= d) ? partial[t - d] : 0;
        __syncthreads();
        partial[t] += v;
        __syncthreads();
    }
    int base = partial[t] - s;      // exclusive
    #pragma unroll
    for (int i = 0; i < 16; ++i) offs[t * 16 + i] = base + loc[i];
}

// ---- sort 3: scatter points to sorted order ----
__global__ void sort_scatter(const float* __restrict__ x, const unsigned short* __restrict__ cell_id,
                             int* __restrict__ offs, float4* __restrict__ spts) {
    int p = blockIdx.x * blockDim.x + threadIdx.x;
    int c = cell_id[p];
    int pos = atomicAdd(&offs[c], 1);
    spts[pos] = make_float4(x[p * 3 + 0], x[p * 3 + 1], x[p * 3 + 2], __int_as_float(p));
}

// ---- per-grid gather prep: corner addresses + weights (bricked layout) ----
struct GP {
    int xp0, xp1, yp0, yp1, zp0, zp1;
    float wx0, wx1, wy0, wy1, wz0, wz1;
    const unsigned int* vg;
};
__device__ inline GP gprep(int g, float ix, float iy, float iz,
                           const unsigned int* __restrict__ vox) {
    GP p;
    float fx = floorf(ix), fy = floorf(iy), fz = floorf(iz);
    int x0 = (int)fx, y0 = (int)fy, z0 = (int)fz;
    float wx = ix - fx, wy = iy - fy, wz = iz - fz;
    p.wx0 = (x0 >= 0) ? (1.0f - wx) : 0.0f;
    p.wx1 = (x0 < 63) ? wx : 0.0f;
    p.wy0 = (y0 >= 0) ? (1.0f - wy) : 0.0f;
    p.wy1 = (y0 < 63) ? wy : 0.0f;
    p.wz0 = (z0 >= 0) ? (1.0f - wz) : 0.0f;
    p.wz1 = (z0 < 63) ? wz : 0.0f;
    int xc0 = max(x0, 0), xc1 = min(x0 + 1, 63);
    int yc0 = max(y0, 0), yc1 = min(y0 + 1, 63);
    int zc0 = max(z0, 0), zc1 = min(z0 + 1, 63);
    p.xp0 = ((xc0 >> 1) << 3) | (xc0 & 1);
    p.xp1 = ((xc1 >> 1) << 3) | (xc1 & 1);
    p.yp0 = ((yc0 >> 1) << 8) | ((yc0 & 1) << 1);
    p.yp1 = ((yc1 >> 1) << 8) | ((yc1 & 1) << 1);
    p.zp0 = ((zc0 >> 1) << 13) | ((zc0 & 1) << 2);
    p.zp1 = ((zc1 >> 1) << 13) | ((zc1 & 1) << 2);
    p.vg = vox + ((size_t)g << 18);
    return p;
}

// ---- paired gather: 16 loads issued together, then both FMA trees ----
// wrA/wrB: per-lane write predicates (invalid lanes of partial grids skip the
// write; clamped addresses are always in-bounds so the loads are safe).
__device__ inline void gather2(int pt, int gA, float axi, float ayi, float azi, bool wrA,
                               int gB, float bxi, float byi, float bzi, bool wrB,
                               const unsigned int* __restrict__ vox,
                               unsigned short* Fsh) {
    GP a = gprep(gA, axi, ayi, azi, vox);
    GP b = gprep(gB, bxi, byi, bzi, vox);
    // issue all 16 loads back-to-back (independent -> overlapped latency)
    unsigned int a00 = a.vg[a.zp0 + a.yp0 + a.xp0], a01 = a.vg[a.zp0 + a.yp0 + a.xp1];
    unsigned int a10 = a.vg[a.zp0 + a.yp1 + a.xp0], a11 = a.vg[a.zp0 + a.yp1 + a.xp1];
    unsigned int a20 = a.vg[a.zp1 + a.yp0 + a.xp0], a21 = a.vg[a.zp1 + a.yp0 + a.xp1];
    unsigned int a30 = a.vg[a.zp1 + a.yp1 + a.xp0], a31 = a.vg[a.zp1 + a.yp1 + a.xp1];
    unsigned int b00 = b.vg[b.zp0 + b.yp0 + b.xp0], b01 = b.vg[b.zp0 + b.yp0 + b.xp1];
    unsigned int b10 = b.vg[b.zp0 + b.yp1 + b.xp0], b11 = b.vg[b.zp0 + b.yp1 + b.xp1];
    unsigned int b20 = b.vg[b.zp1 + b.yp0 + b.xp0], b21 = b.vg[b.zp1 + b.yp0 + b.xp1];
    unsigned int b30 = b.vg[b.zp1 + b.yp1 + b.xp0], b31 = b.vg[b.zp1 + b.yp1 + b.xp1];
    // grid A: accumulation order identical to original (z0y0, z0y1, z1y0, z1y1)
    {
        float f0 = 0.f, f1 = 0.f, wzy;
        wzy = a.wz0 * a.wy0;
        f0 += wzy * (a.wx0 * bflo(a00) + a.wx1 * bflo(a01));
        f1 += wzy * (a.wx0 * bfhi(a00) + a.wx1 * bfhi(a01));
        wzy = a.wz0 * a.wy1;
        f0 += wzy * (a.wx0 * bflo(a10) + a.wx1 * bflo(a11));
        f1 += wzy * (a.wx0 * bfhi(a10) + a.wx1 * bfhi(a11));
        wzy = a.wz1 * a.wy0;
        f0 += wzy * (a.wx0 * bflo(a20) + a.wx1 * bflo(a21));
        f1 += wzy * (a.wx0 * bfhi(a20) + a.wx1 * bfhi(a21));
        wzy = a.wz1 * a.wy1;
        f0 += wzy * (a.wx0 * bflo(a30) + a.wx1 * bflo(a31));
        f1 += wzy * (a.wx0 * bfhi(a30) + a.wx1 * bfhi(a31));
        if (wrA) *(unsigned int*)&Fsh[pt * SF + 36 + 2 * gA] = pk2(f0, f1);
    }
    // grid B
    {
        float f0 = 0.f, f1 = 0.f, wzy;
        wzy = b.wz0 * b.wy0;
        f0 += wzy * (b.wx0 * bflo(b00) + b.wx1 * bflo(b01));
        f1 += wzy * (b.wx0 * bfhi(b00) + b.wx1 * bfhi(b01));
        wzy = b.wz0 * b.wy1;
        f0 += wzy * (b.wx0 * bflo(b10) + b.wx1 * bflo(b11));
        f1 += wzy * (b.wx0 * bfhi(b10) + b.wx1 * bfhi(b11));
        wzy = b.wz1 * b.wy0;
        f0 += wzy * (b.wx0 * bflo(b20) + b.wx1 * bflo(b21));
        f1 += wzy * (b.wx0 * bfhi(b20) + b.wx1 * bfhi(b21));
        wzy = b.wz1 * b.wy1;
        f0 += wzy * (b.wx0 * bflo(b30) + b.wx1 * bflo(b31));
        f1 += wzy * (b.wx0 * bfhi(b30) + b.wx1 * bfhi(b31));
        if (wrB) *(unsigned int*)&Fsh[pt * SF + 36 + 2 * gB] = pk2(f0, f1);
    }
}

__device__ inline void gather1(int pt, int g, float ix, float iy, float iz, bool wr,
                               const unsigned int* __restrict__ vox,
                               unsigned short* Fsh) {
    GP a = gprep(g, ix, iy, iz, vox);
    unsigned int a00 = a.vg[a.zp0 + a.yp0 + a.xp0], a01 = a.vg[a.zp0 + a.yp0 + a.xp1];
    unsigned int a10 = a.vg[a.zp0 + a.yp1 + a.xp0], a11 = a.vg[a.zp0 + a.yp1 + a.xp1];
    unsigned int a20 = a.vg[a.zp1 + a.yp0 + a.xp0], a21 = a.vg[a.zp1 + a.yp0 + a.xp1];
    unsigned int a30 = a.vg[a.zp1 + a.yp1 + a.xp0], a31 = a.vg[a.zp1 + a.yp1 + a.xp1];
    float f0 = 0.f, f1 = 0.f, wzy;
    wzy = a.wz0 * a.wy0;
    f0 += wzy * (a.wx0 * bflo(a00) + a.wx1 * bflo(a01));
    f1 += wzy * (a.wx0 * bfhi(a00) + a.wx1 * bfhi(a01));
    wzy = a.wz0 * a.wy1;
    f0 += wzy * (a.wx0 * bflo(a10) + a.wx1 * bflo(a11));
    f1 += wzy * (a.wx0 * bfhi(a10) + a.wx1 * bfhi(a11));
    wzy = a.wz1 * a.wy0;
    f0 += wzy * (a.wx0 * bflo(a20) + a.wx1 * bflo(a21));
    f1 += wzy * (a.wx0 * bfhi(a20) + a.wx1 * bfhi(a21));
    wzy = a.wz1 * a.wy1;
    f0 += wzy * (a.wx0 * bflo(a30) + a.wx1 * bflo(a31));
    f1 += wzy * (a.wx0 * bfhi(a30) + a.wx1 * bfhi(a31));
    if (wr) *(unsigned int*)&Fsh[pt * SF + 36 + 2 * g] = pk2(f0, f1);
}

// ---- main fused kernel (sorted points, indirect output) ----
__global__ void __launch_bounds__(256, 5)
amrsrn_main(const float4* __restrict__ spts,
            const float* __restrict__ gscale,
            const float* __restrict__ gtrans,
            const unsigned int* __restrict__ vox,
            const unsigned short* __restrict__ w0t,
            const unsigned short* __restrict__ w1t,
            const float* __restrict__ b0,
            const float* __restrict__ b1,
            const float* __restrict__ W2,
            const float* __restrict__ b2,
            float* __restrict__ out) {
    __shared__ unsigned short Fsh[TILE * SF];   // 25600 B
    __shared__ int   sidx[TILE];
    __shared__ float gss[NG * 3];
    __shared__ float gts[NG * 3];

    const int tid = threadIdx.x;
    const int lane = tid & 63;
    const int wv = tid >> 6;
    // Fine-grained XCD interleave: each XCD gets Morton runs of 32 blocks,
    // runs strided 256 apart -> heavy regions spread across XCDs AND the
    // dispatch timeline (no heavy-tail straggle).  Bijective on [0,8192).
    const int cb = ((blockIdx.x >> 8) << 8) | ((blockIdx.x & 7) << 5) | ((blockIdx.x >> 3) & 31);
    const int base = cb * TILE;

    // ---- phase 0: zero F, stage tables; every thread holds its own point ----
    for (int i = tid; i < TILE * SF / 8; i += 256) ((uint4*)Fsh)[i] = make_uint4(0,0,0,0);
    float4 sp = spts[base + lane];          // all 4 waves load same 64 pts (L1)
    const float px = sp.x, py = sp.y, pz = sp.z;
    if (tid < TILE) sidx[tid] = __float_as_int(sp.w);
    if (tid < NG * 3) { gss[tid] = gscale[tid]; gts[tid] = gtrans[tid]; }
    __syncthreads();

    // ---- phase 1a: block AABB + per-grid classification ----
    float lox = px, hix = px, loy = py, hiy = py, loz = pz, hiz = pz;
    #pragma unroll
    for (int m = 1; m < 64; m <<= 1) {
        lox = fminf(lox, __shfl_xor(lox, m)); hix = fmaxf(hix, __shfl_xor(hix, m));
        loy = fminf(loy, __shfl_xor(loy, m)); hiy = fmaxf(hiy, __shfl_xor(hiy, m));
        loz = fminf(loz, __shfl_xor(loz, m)); hiz = fmaxf(hiz, __shfl_xor(hiz, m));
    }
    unsigned long long mfull, mpart;
    {
        int g = lane;                       // lane <-> grid
        float s0 = gss[g*3+0], s1 = gss[g*3+1], s2 = gss[g*3+2];
        float t0 = gts[g*3+0], t1 = gts[g*3+1], t2 = gts[g*3+2];
        float xl = (lox*s0 + t0 + 1.0f)*31.5f, xh = (hix*s0 + t0 + 1.0f)*31.5f;
        float yl = (loy*s1 + t1 + 1.0f)*31.5f, yh = (hiy*s1 + t1 + 1.0f)*31.5f;
        float zl = (loz*s2 + t2 + 1.0f)*31.5f, zh = (hiz*s2 + t2 + 1.0f)*31.5f;
        bool fullg = (xl >= -0.999f) & (xh <= 63.999f)
                   & (yl >= -0.999f) & (yh <= 63.999f)
                   & (zl >= -0.999f) & (zh <= 63.999f);
        bool outg  = (xh < -1.001f) | (xl >= 64.001f)
                   | (yh < -1.001f) | (yl >= 64.001f)
                   | (zh < -1.001f) | (zl >= 64.001f);
        mfull = __ballot(fullg);
        mpart = __ballot(!fullg && !outg);
    }

    // ---- phase 1b: positional encoding (cols 0..35) ----
    {
        #pragma unroll
        for (int t = 0; t < 9; ++t) {
            int tau = wv * 9 + t;
            int tt = (tau < 18) ? tau : tau - 18;
            int l = tt / 3, d = tt - l * 3;
            float c = (d == 0) ? px : ((d == 1) ? py : pz);
            float ang = c * (3.14159265358979323846f * (float)(1 << l));
            float val = (tau < 18) ? __sinf(ang) : __cosf(ang);
            Fsh[lane * SF + tau] = f2bf(val);
        }
    }

    // ---- phase 1c: gathers, paired for latency overlap ----
    {
        int idx = 0;
        int gq = -1; float qx = 0.f, qy = 0.f, qz = 0.f; bool qw = false;
        #pragma unroll 1
        for (int pass = 0; pass < 2; ++pass) {
            unsigned long long m = pass ? mpart : mfull;
            while (m) {
                int g = __builtin_ctzll(m);
                m &= m - 1;
                if ((idx++ & 3) != wv) continue;
                float ix = (px * gss[g*3+0] + gts[g*3+0] + 1.0f) * 31.5f;
                float iy = (py * gss[g*3+1] + gts[g*3+1] + 1.0f) * 31.5f;
                float iz = (pz * gss[g*3+2] + gts[g*3+2] + 1.0f) * 31.5f;
                bool wr = true;
                if (pass) {
                    wr = (ix >= -1.0f) & (ix < 64.0f)
                       & (iy >= -1.0f) & (iy < 64.0f)
                       & (iz >= -1.0f) & (iz < 64.0f);
                }
                if (gq < 0) { gq = g; qx = ix; qy = iy; qz = iz; qw = wr; }
                else {
                    gather2(lane, gq, qx, qy, qz, qw, g, ix, iy, iz, wr, vox, Fsh);
                    gq = -1;
                }
            }
        }
        if (gq >= 0) gather1(lane, gq, qx, qy, qz, qw, vox, Fsh);
    }
    __syncthreads();

    // ---- phase 2: MFMA MLP. wave w owns pts [16w, 16w+16) ----
    const int ptb = wv * 16;
    const int row = lane & 15;
    const int quad = lane >> 4;
    const int koff = quad * 8;

    f32x4 acc0[4] = {{0,0,0,0},{0,0,0,0},{0,0,0,0},{0,0,0,0}};
    #pragma unroll
    for (int ks = 0; ks < 6; ++ks) {
        bf16x8 a = *(const bf16x8*)&Fsh[(ptb + row) * SF + ks * 32 + koff];
        #pragma unroll
        for (int nt = 0; nt < 4; ++nt) {
            bf16x8 b = *(const bf16x8*)&w0t[(nt * 16 + row) * K0 + ks * 32 + koff];
            acc0[nt] = __builtin_amdgcn_mfma_f32_16x16x32_bf16(a, b, acc0[nt], 0, 0, 0);
        }
    }
    #pragma unroll
    for (int nt = 0; nt < 4; ++nt) {
        int node = nt * 16 + row;
        float bb = b0[node];
        #pragma unroll
        for (int r = 0; r < 4; ++r) {
            float h = acc0[nt][r] + bb;
            float s = __sinf(h);
            h = 0.5f * h + s * s;
            Fsh[(ptb + quad * 4 + r) * SF + node] = f2bf(h);
        }
    }

    f32x4 acc1[4] = {{0,0,0,0},{0,0,0,0},{0,0,0,0},{0,0,0,0}};
    #pragma unroll
    for (int ks = 0; ks < 2; ++ks) {
        bf16x8 a = *(const bf16x8*)&Fsh[(ptb + row) * SF + ks * 32 + koff];
        #pragma unroll
        for (int nt = 0; nt < 4; ++nt) {
            bf16x8 b = *(const bf16x8*)&w1t[(nt * 16 + row) * NODES + ks * 32 + koff];
            acc1[nt] = __builtin_amdgcn_mfma_f32_16x16x32_bf16(a, b, acc1[nt], 0, 0, 0);
        }
    }
    float part[4] = {0.f, 0.f, 0.f, 0.f};
    #pragma unroll
    for (int nt = 0; nt < 4; ++nt) {
        int node = nt * 16 + row;
        float b1v = b1[node];
        float w2v = W2[node];
        #pragma unroll
        for (int r = 0; r < 4; ++r) {
            float h = acc1[nt][r] + b1v;
            float s = __sinf(h);
            h = 0.5f * h + s * s;
            part[r] += h * w2v;
        }
    }
    #pragma unroll
    for (int m = 1; m < 16; m <<= 1) {
        #pragma unroll
        for (int r = 0; r < 4; ++r) part[r] += __shfl_xor(part[r], m);
    }
    if (row == 0) {
        float b2v = b2[0];
        #pragma unroll
        for (int r = 0; r < 4; ++r) {
            int pt = ptb + quad * 4 + r;
            out[sidx[pt]] = part[r] + b2v;
        }
    }
}

// ---- fallback (no workspace): direct fp32 kernel ----
__global__ void amrsrn_fallback(const float* __restrict__ x,
                                const float* __restrict__ gscale,
                                const float* __restrict__ gtrans,
                                const float* __restrict__ fg,
                                const float* __restrict__ W0,
                                const float* __restrict__ b0,
                                const float* __restrict__ W1,
                                const float* __restrict__ b1,
                                const float* __restrict__ W2,
                                const float* __restrict__ b2,
                                float* __restrict__ out) {
    int p = blockIdx.x * blockDim.x + threadIdx.x;
    float px = x[p*3+0], py = x[p*3+1], pz = x[p*3+2];
    float h0[NODES];
    #pragma unroll
    for (int j = 0; j < NODES; ++j) h0[j] = b0[j];
    #pragma unroll
    for (int l = 0; l < 6; ++l) {
        float freq = 3.14159265358979323846f * (float)(1 << l);
        #pragma unroll
        for (int d = 0; d < 3; ++d) {
            float v = (d == 0 ? px : (d == 1 ? py : pz)) * freq;
            float s = __sinf(v), c = __cosf(v);
            const float* wrs = W0 + (l*3 + d) * NODES;
            const float* wrc = W0 + (18 + l*3 + d) * NODES;
            #pragma unroll
            for (int j = 0; j < NODES; ++j) h0[j] += s * wrs[j] + c * wrc[j];
        }
    }
    for (int g = 0; g < NG; ++g) {
        float ix = (px * gscale[g*3+0] + gtrans[g*3+0] + 1.0f) * 31.5f;
        float iy = (py * gscale[g*3+1] + gtrans[g*3+1] + 1.0f) * 31.5f;
        float iz = (pz * gscale[g*3+2] + gtrans[g*3+2] + 1.0f) * 31.5f;
        float fxf = floorf(ix), fyf = floorf(iy), fzf = floorf(iz);
        int x0 = (int)fxf, y0 = (int)fyf, z0 = (int)fzf;
        float wx = ix - fxf, wy = iy - fyf, wz = iz - fzf;
        bool any = (x0 >= -1 && x0 < GSZ) && (y0 >= -1 && y0 < GSZ) && (z0 >= -1 && z0 < GSZ);
        if (any) {
            float f0 = 0.f, f1 = 0.f;
            #pragma unroll
            for (int dz = 0; dz < 2; ++dz) {
                int zi = z0 + dz; bool vz = ((unsigned)zi < (unsigned)GSZ);
                int zc = min(max(zi, 0), GSZ - 1);
                float wzf = dz ? wz : 1.f - wz;
                #pragma unroll
                for (int dy = 0; dy < 2; ++dy) {
                    int yi = y0 + dy; bool vy = ((unsigned)yi < (unsigned)GSZ);
                    int yc = min(max(yi, 0), GSZ - 1);
                    float wyf = dy ? wy : 1.f - wy;
                    int rowoff = (zc * GSZ + yc) * GSZ;
                    #pragma unroll
                    for (int dx = 0; dx < 2; ++dx) {
                        int xi = x0 + dx; bool vx = ((unsigned)xi < (unsigned)GSZ);
                        int xc = min(max(xi, 0), GSZ - 1);
                        float w = wzf * wyf * (dx ? wx : 1.f - wx);
                        w = (vz && vy && vx) ? w : 0.f;
                        const float* gp = fg + ((size_t)g << 19);
                        f0 += w * gp[rowoff + xc];
                        f1 += w * gp[VOX + rowoff + xc];
                    }
                }
            }
            const float* wr = W0 + (36 + 2*g) * NODES;
            #pragma unroll
            for (int j = 0; j < NODES; ++j) h0[j] += f0 * wr[j] + f1 * wr[NODES + j];
        }
    }
    #pragma unroll
    for (int j = 0; j < NODES; ++j) { float s = __sinf(h0[j]); h0[j] = 0.5f * h0[j] + s * s; }
    float out_acc = b2[0];
    #pragma unroll
    for (int half = 0; half < 2; ++half) {
        float h1[32];
        #pragma unroll
        for (int j = 0; j < 32; ++j) h1[j] = b1[half*32 + j];
        #pragma unroll
        for (int i = 0; i < NODES; ++i) {
            float a = h0[i];
            const float* w1r = W1 + i * NODES + half*32;
            #pragma unroll
            for (int j = 0; j < 32; ++j) h1[j] += a * w1r[j];
        }
        #pragma unroll
        for (int j = 0; j < 32; ++j) { float s = __sinf(h1[j]); out_acc += (0.5f * h1[j] + s * s) * W2[half*32 + j]; }
    }
    out[p] = out_acc;
}

extern "C" void kernel_launch(void* const* d_in, const int* in_sizes, int n_in,
                              void* d_out, int out_size, void* d_ws, size_t ws_size,
                              hipStream_t stream) {
    const float* x      = (const float*)d_in[0];
    const float* gscale = (const float*)d_in[1];
    const float* gtrans = (const float*)d_in[2];
    const float* fg     = (const float*)d_in[3];
    const float* W0     = (const float*)d_in[4];
    const float* b0     = (const float*)d_in[5];
    const float* W1     = (const float*)d_in[6];
    const float* b1     = (const float*)d_in[7];
    const float* W2     = (const float*)d_in[8];
    const float* b2     = (const float*)d_in[9];
    float* out = (float*)d_out;

    char* wsp = (char*)d_ws;
    unsigned short* w0t = (unsigned short*)wsp;
    unsigned short* w1t = w0t + NODES * K0;
    int* hist           = (int*)(wsp + (64 << 10));
    int* offs           = (int*)(wsp + (80 << 10));
    unsigned short* cid = (unsigned short*)(wsp + (96 << 10));
    float4* spts        = (float4*)(wsp + (96 << 10) + (1 << 20));
    unsigned int* vox   = (unsigned int*)(wsp + (96 << 10) + (1 << 20) + (8 << 20));
    const size_t ws_needed = (96 << 10) + (1 << 20) + (8 << 20) + (size_t)NG * VOX * 4;

    if (ws_size >= ws_needed) {
        hipMemsetAsync(hist, 0, NCELL * sizeof(int), stream);
        prep_fused<<<PREP_VB + PREP_CB + 16, 256, 0, stream>>>(
            fg, (uint4*)vox, x, cid, hist, W0, W1, w0t, w1t);
        sort_scan<<<1, 256, 0, stream>>>(hist, offs);
        sort_scatter<<<NPTS / 256, 256, 0, stream>>>(x, cid, offs, spts);
        amrsrn_main<<<NBLK, 256, 0, stream>>>(spts, gscale, gtrans, vox,
                                              w0t, w1t, b0, b1, W2, b2, out);
    } else {
        amrsrn_fallback<<<NPTS / 256, 256, 0, stream>>>(
            x, gscale, gtrans, fg, W0, b0, W1, b1, W2, b2, out);
    }
}

// Round 5
// 395.401 us; speedup vs baseline: 1.2626x; 1.1334x over previous
//
#include <hip/hip_runtime.h>
#include <hip/hip_bf16.h>

#define NPTS    524288
#define NG      64
#define GSZ     64
#define VOX     (GSZ*GSZ*GSZ)       // 262144
#define NODES   64
#define TILE    64                  // points per block
#define NBLK    (NPTS / TILE)       // 8192
#define K0      192                 // padded K for layer-0 (164 -> 192)
#define SF      200                 // Fsh row stride (bf16) - natural bank stagger
#define NCELL   4096                // 16^3 Morton cells
#define PREP_VB 16384               // vox-repack blocks in prep_fused
#define PREP_CB 2048                // sort-count blocks in prep_fused

typedef __attribute__((ext_vector_type(8))) short bf16x8;
typedef __attribute__((ext_vector_type(4))) float f32x4;

__device__ inline unsigned short f2bf(float f) {
    __hip_bfloat16 b = __float2bfloat16(f);
    union { __hip_bfloat16 h; unsigned short u; } cv; cv.h = b;
    return cv.u;
}
__device__ inline unsigned int pk2(float c0, float c1) {
    return (unsigned int)f2bf(c0) | ((unsigned int)f2bf(c1) << 16);
}
__device__ inline float bflo(unsigned int v) { return __uint_as_float(v << 16); }
__device__ inline float bfhi(unsigned int v) { return __uint_as_float(v & 0xffff0000u); }

__device__ inline int spread4(int v) {   // 4 bits -> bits 0,3,6,9
    return (v & 1) | ((v & 2) << 2) | ((v & 4) << 4) | ((v & 8) << 6);
}
__device__ inline int cell_of(float px, float py, float pz) {
    int cx = min(max((int)((px + 1.0f) * 8.0f), 0), 15);
    int cy = min(max((int)((py + 1.0f) * 8.0f), 0), 15);
    int cz = min(max((int)((pz + 1.0f) * 8.0f), 0), 15);
    return spread4(cx) | (spread4(cy) << 1) | (spread4(cz) << 2);
}

// Bricked vox layout: 2x2x2-voxel bricks (8 u32 = 32B), bricks linear in
// (bz,by,bx).  idx = (bz<<13 | by<<8 | bx<<3) + (lz<<2 | ly<<1 | lx).

// ---- fused prep: vox brick-repack + sort histogram + weight prep ----
// Weights are stored FRAGMENT-CONTIGUOUS: w0f[((ks*4+nt)*64 + lane)*8 + j]
// holds W0[(ks*32 + (lane>>4)*8 + j)*64 + nt*16 + (lane&15)] (bf16, 0-pad
// k>=164), so each MFMA B-read is one fully-coalesced 1KiB wave load.
__global__ void prep_fused(const float* __restrict__ fg, uint4* __restrict__ vox4,
                           const float* __restrict__ x, unsigned short* __restrict__ cid,
                           int* __restrict__ hist,
                           const float* __restrict__ W0, const float* __restrict__ W1,
                           unsigned short* __restrict__ w0f, unsigned short* __restrict__ w1f) {
    int b = blockIdx.x;
    int tid = threadIdx.x;
    if (b < PREP_VB) {
        int idx = b * 256 + tid;            // NG * VOX/4 total
        int g = idx >> 16;
        int hb = idx & 65535;
        int brick = hb >> 1;
        int h = hb & 1;                      // lz
        int bx = brick & 31, by = (brick >> 5) & 31, bz = brick >> 10;
        int xx = bx << 1, yy = by << 1, zz = (bz << 1) + h;
        const float* c0 = fg + (size_t)g * (2 * VOX) + ((zz << 6) + yy) * 64 + xx;
        const float* c1 = c0 + VOX;
        float2 a0 = *(const float2*)c0;
        float2 a1 = *(const float2*)(c0 + 64);
        float2 d0 = *(const float2*)c1;
        float2 d1 = *(const float2*)(c1 + 64);
        vox4[idx] = make_uint4(pk2(a0.x, d0.x), pk2(a0.y, d0.y),
                               pk2(a1.x, d1.x), pk2(a1.y, d1.y));
    } else if (b < PREP_VB + PREP_CB) {
        int p = (b - PREP_VB) * 256 + tid;
        int c = cell_of(x[p * 3 + 0], x[p * 3 + 1], x[p * 3 + 2]);
        cid[p] = (unsigned short)c;
        atomicAdd(&hist[c], 1);
    } else {
        int t = (b - PREP_VB - PREP_CB) * 256 + tid;   // 0..4095
        for (int i = t; i < 24 * 512; i += 4096) {     // w0f: 6ks*4nt*64*8 shorts
            int j = i & 7, ln = (i >> 3) & 63, fi = i >> 9;   // fi = ks*4+nt
            int ks = fi >> 2, nt = fi & 3;
            int k = ks * 32 + ((ln >> 4) << 3) + j, n = nt * 16 + (ln & 15);
            w0f[i] = (k < 164) ? f2bf(W0[k * NODES + n]) : (unsigned short)0;
        }
        {   // w1f: 2ks*4nt*64*8 = 4096 shorts, one per thread
            int i = t;
            int j = i & 7, ln = (i >> 3) & 63, fi = i >> 9;
            int ks = fi >> 2, nt = fi & 3;
            int k = ks * 32 + ((ln >> 4) << 3) + j, n = nt * 16 + (ln & 15);
            w1f[i] = f2bf(W1[k * NODES + n]);
        }
    }
}

// ---- sort 2: exclusive scan of 4096 bins ----
__global__ void sort_scan(const int* __restrict__ hist, int* __restrict__ offs) {
    __shared__ int partial[256];
    int t = threadIdx.x;
    int loc[16];
    int s = 0;
    #pragma unroll
    for (int i = 0; i < 16; ++i) { loc[i] = s; s += hist[t * 16 + i]; }
    partial[t] = s;
    __syncthreads();
    for (int d = 1; d < 256; d <<= 1) {
        int v = (t >= d) ? partial[t - d] : 0;
        __syncthreads();
        partial[t] += v;
        __syncthreads();
    }
    int base = partial[t] - s;      // exclusive
    #pragma unroll
    for (int i = 0; i < 16; ++i) offs[t * 16 + i] = base + loc[i];
}

// ---- sort 3: scatter points to sorted order ----
__global__ void sort_scatter(const float* __restrict__ x, const unsigned short* __restrict__ cell_id,
                             int* __restrict__ offs, float4* __restrict__ spts) {
    int p = blockIdx.x * blockDim.x + threadIdx.x;
    int c = cell_id[p];
    int pos = atomicAdd(&offs[c], 1);
    spts[pos] = make_float4(x[p * 3 + 0], x[p * 3 + 1], x[p * 3 + 2], __int_as_float(p));
}

// ---- per-grid gather prep: corner addresses + weights (bricked layout) ----
struct GP {
    int xp0, xp1, yp0, yp1, zp0, zp1;
    float wx0, wx1, wy0, wy1, wz0, wz1;
    const unsigned int* vg;
};
__device__ inline GP gprep(int g, float ix, float iy, float iz,
                           const unsigned int* __restrict__ vox) {
    GP p;
    float fx = floorf(ix), fy = floorf(iy), fz = floorf(iz);
    int x0 = (int)fx, y0 = (int)fy, z0 = (int)fz;
    float wx = ix - fx, wy = iy - fy, wz = iz - fz;
    p.wx0 = (x0 >= 0) ? (1.0f - wx) : 0.0f;
    p.wx1 = (x0 < 63) ? wx : 0.0f;
    p.wy0 = (y0 >= 0) ? (1.0f - wy) : 0.0f;
    p.wy1 = (y0 < 63) ? wy : 0.0f;
    p.wz0 = (z0 >= 0) ? (1.0f - wz) : 0.0f;
    p.wz1 = (z0 < 63) ? wz : 0.0f;
    int xc0 = max(x0, 0), xc1 = min(x0 + 1, 63);
    int yc0 = max(y0, 0), yc1 = min(y0 + 1, 63);
    int zc0 = max(z0, 0), zc1 = min(z0 + 1, 63);
    p.xp0 = ((xc0 >> 1) << 3) | (xc0 & 1);
    p.xp1 = ((xc1 >> 1) << 3) | (xc1 & 1);
    p.yp0 = ((yc0 >> 1) << 8) | ((yc0 & 1) << 1);
    p.yp1 = ((yc1 >> 1) << 8) | ((yc1 & 1) << 1);
    p.zp0 = ((zc0 >> 1) << 13) | ((zc0 & 1) << 2);
    p.zp1 = ((zc1 >> 1) << 13) | ((zc1 & 1) << 2);
    p.vg = vox + ((size_t)g << 18);
    return p;
}

// ---- paired gather: 16 loads issued together, then both FMA trees ----
__device__ inline void gather2(int pt, int gA, float axi, float ayi, float azi, bool wrA,
                               int gB, float bxi, float byi, float bzi, bool wrB,
                               const unsigned int* __restrict__ vox,
                               unsigned short* Fsh) {
    GP a = gprep(gA, axi, ayi, azi, vox);
    GP b = gprep(gB, bxi, byi, bzi, vox);
    unsigned int a00 = a.vg[a.zp0 + a.yp0 + a.xp0], a01 = a.vg[a.zp0 + a.yp0 + a.xp1];
    unsigned int a10 = a.vg[a.zp0 + a.yp1 + a.xp0], a11 = a.vg[a.zp0 + a.yp1 + a.xp1];
    unsigned int a20 = a.vg[a.zp1 + a.yp0 + a.xp0], a21 = a.vg[a.zp1 + a.yp0 + a.xp1];
    unsigned int a30 = a.vg[a.zp1 + a.yp1 + a.xp0], a31 = a.vg[a.zp1 + a.yp1 + a.xp1];
    unsigned int b00 = b.vg[b.zp0 + b.yp0 + b.xp0], b01 = b.vg[b.zp0 + b.yp0 + b.xp1];
    unsigned int b10 = b.vg[b.zp0 + b.yp1 + b.xp0], b11 = b.vg[b.zp0 + b.yp1 + b.xp1];
    unsigned int b20 = b.vg[b.zp1 + b.yp0 + b.xp0], b21 = b.vg[b.zp1 + b.yp0 + b.xp1];
    unsigned int b30 = b.vg[b.zp1 + b.yp1 + b.xp0], b31 = b.vg[b.zp1 + b.yp1 + b.xp1];
    {
        float f0 = 0.f, f1 = 0.f, wzy;
        wzy = a.wz0 * a.wy0;
        f0 += wzy * (a.wx0 * bflo(a00) + a.wx1 * bflo(a01));
        f1 += wzy * (a.wx0 * bfhi(a00) + a.wx1 * bfhi(a01));
        wzy = a.wz0 * a.wy1;
        f0 += wzy * (a.wx0 * bflo(a10) + a.wx1 * bflo(a11));
        f1 += wzy * (a.wx0 * bfhi(a10) + a.wx1 * bfhi(a11));
        wzy = a.wz1 * a.wy0;
        f0 += wzy * (a.wx0 * bflo(a20) + a.wx1 * bflo(a21));
        f1 += wzy * (a.wx0 * bfhi(a20) + a.wx1 * bfhi(a21));
        wzy = a.wz1 * a.wy1;
        f0 += wzy * (a.wx0 * bflo(a30) + a.wx1 * bflo(a31));
        f1 += wzy * (a.wx0 * bfhi(a30) + a.wx1 * bfhi(a31));
        if (wrA) *(unsigned int*)&Fsh[pt * SF + 36 + 2 * gA] = pk2(f0, f1);
    }
    {
        float f0 = 0.f, f1 = 0.f, wzy;
        wzy = b.wz0 * b.wy0;
        f0 += wzy * (b.wx0 * bflo(b00) + b.wx1 * bflo(b01));
        f1 += wzy * (b.wx0 * bfhi(b00) + b.wx1 * bfhi(b01));
        wzy = b.wz0 * b.wy1;
        f0 += wzy * (b.wx0 * bflo(b10) + b.wx1 * bflo(b11));
        f1 += wzy * (b.wx0 * bfhi(b10) + b.wx1 * bfhi(b11));
        wzy = b.wz1 * b.wy0;
        f0 += wzy * (b.wx0 * bflo(b20) + b.wx1 * bflo(b21));
        f1 += wzy * (b.wx0 * bfhi(b20) + b.wx1 * bfhi(b21));
        wzy = b.wz1 * b.wy1;
        f0 += wzy * (b.wx0 * bflo(b30) + b.wx1 * bflo(b31));
        f1 += wzy * (b.wx0 * bfhi(b30) + b.wx1 * bfhi(b31));
        if (wrB) *(unsigned int*)&Fsh[pt * SF + 36 + 2 * gB] = pk2(f0, f1);
    }
}

__device__ inline void gather1(int pt, int g, float ix, float iy, float iz, bool wr,
                               const unsigned int* __restrict__ vox,
                               unsigned short* Fsh) {
    GP a = gprep(g, ix, iy, iz, vox);
    unsigned int a00 = a.vg[a.zp0 + a.yp0 + a.xp0], a01 = a.vg[a.zp0 + a.yp0 + a.xp1];
    unsigned int a10 = a.vg[a.zp0 + a.yp1 + a.xp0], a11 = a.vg[a.zp0 + a.yp1 + a.xp1];
    unsigned int a20 = a.vg[a.zp1 + a.yp0 + a.xp0], a21 = a.vg[a.zp1 + a.yp0 + a.xp1];
    unsigned int a30 = a.vg[a.zp1 + a.yp1 + a.xp0], a31 = a.vg[a.zp1 + a.yp1 + a.xp1];
    float f0 = 0.f, f1 = 0.f, wzy;
    wzy = a.wz0 * a.wy0;
    f0 += wzy * (a.wx0 * bflo(a00) + a.wx1 * bflo(a01));
    f1 += wzy * (a.wx0 * bfhi(a00) + a.wx1 * bfhi(a01));
    wzy = a.wz0 * a.wy1;
    f0 += wzy * (a.wx0 * bflo(a10) + a.wx1 * bflo(a11));
    f1 += wzy * (a.wx0 * bfhi(a10) + a.wx1 * bfhi(a11));
    wzy = a.wz1 * a.wy0;
    f0 += wzy * (a.wx0 * bflo(a20) + a.wx1 * bflo(a21));
    f1 += wzy * (a.wx0 * bfhi(a20) + a.wx1 * bfhi(a21));
    wzy = a.wz1 * a.wy1;
    f0 += wzy * (a.wx0 * bflo(a30) + a.wx1 * bflo(a31));
    f1 += wzy * (a.wx0 * bfhi(a30) + a.wx1 * bfhi(a31));
    if (wr) *(unsigned int*)&Fsh[pt * SF + 36 + 2 * g] = pk2(f0, f1);
}

#define EXTRACT(gv, pv) \
    if (mf) { gv = (int)__builtin_ctzll(mf); mf &= mf - 1; pv = false; } \
    else if (mp) { gv = (int)__builtin_ctzll(mp); mp &= mp - 1; pv = true; } \
    else { gv = 0; pv = true; }

// ---- main fused kernel: BARRIER-FREE. Each wave owns 16 points end-to-end.
// All Fsh accesses are wave-private rows [wv*16, wv*16+16); within-wave LDS
// ordering is program-order, so no __syncthreads anywhere -> waves desync and
// co-load TA / VALU / trans / LDS / MFMA pipes instead of convoying.
__global__ void __launch_bounds__(256, 6)
amrsrn_main(const float4* __restrict__ spts,
            const float* __restrict__ gscale,
            const float* __restrict__ gtrans,
            const unsigned int* __restrict__ vox,
            const unsigned short* __restrict__ w0f,
            const unsigned short* __restrict__ w1f,
            const float* __restrict__ b0,
            const float* __restrict__ b1,
            const float* __restrict__ W2,
            const float* __restrict__ b2,
            float* __restrict__ out) {
    __shared__ unsigned short Fsh[TILE * SF];   // 25600 B (only LDS) -> 6 blk/CU

    const int tid = threadIdx.x;
    const int lane = tid & 63;
    const int wv = tid >> 6;
    // coarse XCD swizzle (R3): contiguous Morton octant per XCD -> L2 reuse
    const int cb = ((blockIdx.x & 7) << 10) | (blockIdx.x >> 3);
    const int base = cb * TILE;
    const int ptb = wv * 16;
    const int ptloc = lane >> 2;                // 16 points per wave
    const int sub = lane & 3;                   // 4 gather slots per point
    const int pt = ptb + ptloc;

    // ---- own point (L1: 4 waves read 4 disjoint 256B segments) ----
    float4 sp = spts[base + pt];
    const float px = sp.x, py = sp.y, pz = sp.z;
    const int sreg = __float_as_int(sp.w);

    // ---- zero own 16 Fsh rows (6400 B) ----
    {
        uint4* zp = (uint4*)(Fsh + ptb * SF);
        for (int i = lane; i < 16 * SF / 8; i += 64) zp[i] = make_uint4(0, 0, 0, 0);
    }

    // ---- PE: 16 pts x 36 taus = 64 lanes x 9 ----
    #pragma unroll
    for (int t = 0; t < 9; ++t) {
        int tau = sub * 9 + t;
        int tt = (tau < 18) ? tau : tau - 18;
        int l = tt / 3, d = tt - l * 3;
        float c = (d == 0) ? px : ((d == 1) ? py : pz);
        float ang = c * (3.14159265358979323846f * (float)(1 << l));
        float val = (tau < 18) ? __sinf(ang) : __cosf(ang);
        Fsh[pt * SF + tau] = f2bf(val);
    }

    // ---- wave AABB (16 pts, each appears 4x) + grid classification ----
    float lox = px, hix = px, loy = py, hiy = py, loz = pz, hiz = pz;
    #pragma unroll
    for (int m = 1; m < 64; m <<= 1) {
        lox = fminf(lox, __shfl_xor(lox, m)); hix = fmaxf(hix, __shfl_xor(hix, m));
        loy = fminf(loy, __shfl_xor(loy, m)); hiy = fmaxf(hiy, __shfl_xor(hiy, m));
        loz = fminf(loz, __shfl_xor(loz, m)); hiz = fmaxf(hiz, __shfl_xor(hiz, m));
    }
    unsigned long long mf, mp;
    {
        int g = lane;
        float s0 = gscale[g*3+0], s1 = gscale[g*3+1], s2 = gscale[g*3+2];
        float t0 = gtrans[g*3+0], t1 = gtrans[g*3+1], t2 = gtrans[g*3+2];
        float xl = (lox*s0 + t0 + 1.0f)*31.5f, xh = (hix*s0 + t0 + 1.0f)*31.5f;
        float yl = (loy*s1 + t1 + 1.0f)*31.5f, yh = (hiy*s1 + t1 + 1.0f)*31.5f;
        float zl = (loz*s2 + t2 + 1.0f)*31.5f, zh = (hiz*s2 + t2 + 1.0f)*31.5f;
        bool fullg = (xl >= -0.999f) & (xh <= 63.999f)
                   & (yl >= -0.999f) & (yh <= 63.999f)
                   & (zl >= -0.999f) & (zh <= 63.999f);
        bool outg  = (xh < -1.001f) | (xl >= 64.001f)
                   | (yh < -1.001f) | (yl >= 64.001f)
                   | (zh < -1.001f) | (zl >= 64.001f);
        mf = __ballot(fullg);
        mp = __ballot(!fullg && !outg);
    }

    // ---- gathers: rounds of 8 grids (2 per sub-slot, paired for ILP) ----
    {
        int total = __popcll(mf) + __popcll(mp);
        int done = 0;
        while (done < total) {
            int g0,g1,g2,g3,g4,g5,g6,g7; bool p0,p1,p2,p3,p4,p5,p6,p7;
            EXTRACT(g0,p0) EXTRACT(g1,p1) EXTRACT(g2,p2) EXTRACT(g3,p3)
            EXTRACT(g4,p4) EXTRACT(g5,p5) EXTRACT(g6,p6) EXTRACT(g7,p7)
            int  gA = sub==0?g0: sub==1?g1: sub==2?g2:g3;
            bool pA = sub==0?p0: sub==1?p1: sub==2?p2:p3;
            bool avA = (done + sub) < total;
            float ixA = (px * gscale[gA*3+0] + gtrans[gA*3+0] + 1.0f) * 31.5f;
            float iyA = (py * gscale[gA*3+1] + gtrans[gA*3+1] + 1.0f) * 31.5f;
            float izA = (pz * gscale[gA*3+2] + gtrans[gA*3+2] + 1.0f) * 31.5f;
            bool wrA = avA && (!pA || ((ixA >= -1.0f) & (ixA < 64.0f)
                                     & (iyA >= -1.0f) & (iyA < 64.0f)
                                     & (izA >= -1.0f) & (izA < 64.0f)));
            if (done + 4 < total) {     // wave-uniform branch
                int  gB = sub==0?g4: sub==1?g5: sub==2?g6:g7;
                bool pB = sub==0?p4: sub==1?p5: sub==2?p6:p7;
                bool avB = (done + 4 + sub) < total;
                float ixB = (px * gscale[gB*3+0] + gtrans[gB*3+0] + 1.0f) * 31.5f;
                float iyB = (py * gscale[gB*3+1] + gtrans[gB*3+1] + 1.0f) * 31.5f;
                float izB = (pz * gscale[gB*3+2] + gtrans[gB*3+2] + 1.0f) * 31.5f;
                bool wrB = avB && (!pB || ((ixB >= -1.0f) & (ixB < 64.0f)
                                         & (iyB >= -1.0f) & (iyB < 64.0f)
                                         & (izB >= -1.0f) & (izB < 64.0f)));
                gather2(pt, gA, ixA, iyA, izA, wrA, gB, ixB, iyB, izB, wrB, vox, Fsh);
            } else {
                gather1(pt, gA, ixA, iyA, izA, wrA, vox, Fsh);
            }
            done += 8;
        }
    }

    // ---- MFMA MLP on own 16 rows (no barrier needed: same wave) ----
    const int row = lane & 15;
    const int quad = lane >> 4;

    f32x4 acc0[4] = {{0,0,0,0},{0,0,0,0},{0,0,0,0},{0,0,0,0}};
    #pragma unroll
    for (int ks = 0; ks < 6; ++ks) {
        bf16x8 a = *(const bf16x8*)&Fsh[(ptb + row) * SF + ks * 32 + quad * 8];
        #pragma unroll
        for (int nt = 0; nt < 4; ++nt) {
            bf16x8 b = *(const bf16x8*)&w0f[(((ks << 2) + nt) << 9) + (lane << 3)];
            acc0[nt] = __builtin_amdgcn_mfma_f32_16x16x32_bf16(a, b, acc0[nt], 0, 0, 0);
        }
    }
    #pragma unroll
    for (int nt = 0; nt < 4; ++nt) {
        int node = nt * 16 + row;
        float bb = b0[node];
        #pragma unroll
        for (int r = 0; r < 4; ++r) {
            float h = acc0[nt][r] + bb;
            float s = __sinf(h);
            h = 0.5f * h + s * s;
            Fsh[(ptb + quad * 4 + r) * SF + node] = f2bf(h);
        }
    }

    f32x4 acc1[4] = {{0,0,0,0},{0,0,0,0},{0,0,0,0},{0,0,0,0}};
    #pragma unroll
    for (int ks = 0; ks < 2; ++ks) {
        bf16x8 a = *(const bf16x8*)&Fsh[(ptb + row) * SF + ks * 32 + quad * 8];
        #pragma unroll
        for (int nt = 0; nt < 4; ++nt) {
            bf16x8 b = *(const bf16x8*)&w1f[(((ks << 2) + nt) << 9) + (lane << 3)];
            acc1[nt] = __builtin_amdgcn_mfma_f32_16x16x32_bf16(a, b, acc1[nt], 0, 0, 0);
        }
    }
    float part[4] = {0.f, 0.f, 0.f, 0.f};
    #pragma unroll
    for (int nt = 0; nt < 4; ++nt) {
        int node = nt * 16 + row;
        float b1v = b1[node];
        float w2v = W2[node];
        #pragma unroll
        for (int r = 0; r < 4; ++r) {
            float h = acc1[nt][r] + b1v;
            float s = __sinf(h);
            h = 0.5f * h + s * s;
            part[r] += h * w2v;
        }
    }
    #pragma unroll
    for (int m = 1; m < 16; m <<= 1) {
        #pragma unroll
        for (int r = 0; r < 4; ++r) part[r] += __shfl_xor(part[r], m);
    }
    // output indices via shfl (all lanes active), then divergent store
    int o0 = __shfl(sreg, (quad * 4 + 0) << 2);
    int o1 = __shfl(sreg, (quad * 4 + 1) << 2);
    int o2 = __shfl(sreg, (quad * 4 + 2) << 2);
    int o3 = __shfl(sreg, (quad * 4 + 3) << 2);
    if (row == 0) {
        float b2v = b2[0];
        out[o0] = part[0] + b2v;
        out[o1] = part[1] + b2v;
        out[o2] = part[2] + b2v;
        out[o3] = part[3] + b2v;
    }
}

// ---- fallback (no workspace): direct fp32 kernel ----
__global__ void amrsrn_fallback(const float* __restrict__ x,
                                const float* __restrict__ gscale,
                                const float* __restrict__ gtrans,
                                const float* __restrict__ fg,
                                const float* __restrict__ W0,
                                const float* __restrict__ b0,
                                const float* __restrict__ W1,
                                const float* __restrict__ b1,
                                const float* __restrict__ W2,
                                const float* __restrict__ b2,
                                float* __restrict__ out) {
    int p = blockIdx.x * blockDim.x + threadIdx.x;
    float px = x[p*3+0], py = x[p*3+1], pz = x[p*3+2];
    float h0[NODES];
    #pragma unroll
    for (int j = 0; j < NODES; ++j) h0[j] = b0[j];
    #pragma unroll
    for (int l = 0; l < 6; ++l) {
        float freq = 3.14159265358979323846f * (float)(1 << l);
        #pragma unroll
        for (int d = 0; d < 3; ++d) {
            float v = (d == 0 ? px : (d == 1 ? py : pz)) * freq;
            float s = __sinf(v), c = __cosf(v);
            const float* wrs = W0 + (l*3 + d) * NODES;
            const float* wrc = W0 + (18 + l*3 + d) * NODES;
            #pragma unroll
            for (int j = 0; j < NODES; ++j) h0[j] += s * wrs[j] + c * wrc[j];
        }
    }
    for (int g = 0; g < NG; ++g) {
        float ix = (px * gscale[g*3+0] + gtrans[g*3+0] + 1.0f) * 31.5f;
        float iy = (py * gscale[g*3+1] + gtrans[g*3+1] + 1.0f) * 31.5f;
        float iz = (pz * gscale[g*3+2] + gtrans[g*3+2] + 1.0f) * 31.5f;
        float fxf = floorf(ix), fyf = floorf(iy), fzf = floorf(iz);
        int x0 = (int)fxf, y0 = (int)fyf, z0 = (int)fzf;
        float wx = ix - fxf, wy = iy - fyf, wz = iz - fzf;
        bool any = (x0 >= -1 && x0 < GSZ) && (y0 >= -1 && y0 < GSZ) && (z0 >= -1 && z0 < GSZ);
        if (any) {
            float f0 = 0.f, f1 = 0.f;
            #pragma unroll
            for (int dz = 0; dz < 2; ++dz) {
                int zi = z0 + dz; bool vz = ((unsigned)zi < (unsigned)GSZ);
                int zc = min(max(zi, 0), GSZ - 1);
                float wzf = dz ? wz : 1.f - wz;
                #pragma unroll
                for (int dy = 0; dy < 2; ++dy) {
                    int yi = y0 + dy; bool vy = ((unsigned)yi < (unsigned)GSZ);
                    int yc = min(max(yi, 0), GSZ - 1);
                    float wyf = dy ? wy : 1.f - wy;
                    int rowoff = (zc * GSZ + yc) * GSZ;
                    #pragma unroll
                    for (int dx = 0; dx < 2; ++dx) {
                        int xi = x0 + dx; bool vx = ((unsigned)xi < (unsigned)GSZ);
                        int xc = min(max(xi, 0), GSZ - 1);
                        float w = wzf * wyf * (dx ? wx : 1.f - wx);
                        w = (vz && vy && vx) ? w : 0.f;
                        const float* gp = fg + ((size_t)g << 19);
                        f0 += w * gp[rowoff + xc];
                        f1 += w * gp[VOX + rowoff + xc];
                    }
                }
            }
            const float* wr = W0 + (36 + 2*g) * NODES;
            #pragma unroll
            for (int j = 0; j < NODES; ++j) h0[j] += f0 * wr[j] + f1 * wr[NODES + j];
        }
    }
    #pragma unroll
    for (int j = 0; j < NODES; ++j) { float s = __sinf(h0[j]); h0[j] = 0.5f * h0[j] + s * s; }
    float out_acc = b2[0];
    #pragma unroll
    for (int half = 0; half < 2; ++half) {
        float h1[32];
        #pragma unroll
        for (int j = 0; j < 32; ++j) h1[j] = b1[half*32 + j];
        #pragma unroll
        for (int i = 0; i < NODES; ++i) {
            float a = h0[i];
            const float* w1r = W1 + i * NODES + half*32;
            #pragma unroll
            for (int j = 0; j < 32; ++j) h1[j] += a * w1r[j];
        }
        #pragma unroll
        for (int j = 0; j < 32; ++j) { float s = __sinf(h1[j]); out_acc += (0.5f * h1[j] + s * s) * W2[half*32 + j]; }
    }
    out[p] = out_acc;
}

extern "C" void kernel_launch(void* const* d_in, const int* in_sizes, int n_in,
                              void* d_out, int out_size, void* d_ws, size_t ws_size,
                              hipStream_t stream) {
    const float* x      = (const float*)d_in[0];
    const float* gscale = (const float*)d_in[1];
    const float* gtrans = (const float*)d_in[2];
    const float* fg     = (const float*)d_in[3];
    const float* W0     = (const float*)d_in[4];
    const float* b0     = (const float*)d_in[5];
    const float* W1     = (const float*)d_in[6];
    const float* b1     = (const float*)d_in[7];
    const float* W2     = (const float*)d_in[8];
    const float* b2     = (const float*)d_in[9];
    float* out = (float*)d_out;

    char* wsp = (char*)d_ws;
    unsigned short* w0f = (unsigned short*)wsp;            // 24576 B
    unsigned short* w1f = w0f + 24 * 512;                  // 8192 B
    int* hist           = (int*)(wsp + (64 << 10));
    int* offs           = (int*)(wsp + (80 << 10));
    unsigned short* cid = (unsigned short*)(wsp + (96 << 10));
    float4* spts        = (float4*)(wsp + (96 << 10) + (1 << 20));
    unsigned int* vox   = (unsigned int*)(wsp + (96 << 10) + (1 << 20) + (8 << 20));
    const size_t ws_needed = (96 << 10) + (1 << 20) + (8 << 20) + (size_t)NG * VOX * 4;

    if (ws_size >= ws_needed) {
        hipMemsetAsync(hist, 0, NCELL * sizeof(int), stream);
        prep_fused<<<PREP_VB + PREP_CB + 16, 256, 0, stream>>>(
            fg, (uint4*)vox, x, cid, hist, W0, W1, w0f, w1f);
        sort_scan<<<1, 256, 0, stream>>>(hist, offs);
        sort_scatter<<<NPTS / 256, 256, 0, stream>>>(x, cid, offs, spts);
        amrsrn_main<<<NBLK, 256, 0, stream>>>(spts, gscale, gtrans, vox,
                                              w0f, w1f, b0, b1, W2, b2, out);
    } else {
        amrsrn_fallback<<<NPTS / 256, 256, 0, stream>>>(
            x, gscale, gtrans, fg, W0, b0, W1, b1, W2, b2, out);
    }
}

// Round 6
// 392.438 us; speedup vs baseline: 1.2721x; 1.0076x over previous
//
#include <hip/hip_runtime.h>
#include <hip/hip_bf16.h>

#define NPTS    524288
#define NG      64
#define GSZ     64
#define VOX     (GSZ*GSZ*GSZ)       // 262144
#define NODES   64
#define TILE    64                  // points per block
#define NBLK    (NPTS / TILE)       // 8192
#define K0      192                 // padded K for layer-0 (164 -> 192)
#define SF      200                 // Fsh row stride (bf16) - natural bank stagger
#define NCELL   4096                // 16^3 Morton cells
#define PREP_VB 16384               // vox-repack blocks in prep_fused
#define PREP_CB 2048                // sort-count blocks in prep_fused

typedef __attribute__((ext_vector_type(8))) short bf16x8;
typedef __attribute__((ext_vector_type(4))) float f32x4;

__device__ inline unsigned short f2bf(float f) {
    __hip_bfloat16 b = __float2bfloat16(f);
    union { __hip_bfloat16 h; unsigned short u; } cv; cv.h = b;
    return cv.u;
}
__device__ inline unsigned int pk2(float c0, float c1) {
    return (unsigned int)f2bf(c0) | ((unsigned int)f2bf(c1) << 16);
}
__device__ inline float bflo(unsigned int v) { return __uint_as_float(v << 16); }
__device__ inline float bfhi(unsigned int v) { return __uint_as_float(v & 0xffff0000u); }

__device__ inline int spread4(int v) {   // 4 bits -> bits 0,3,6,9
    return (v & 1) | ((v & 2) << 2) | ((v & 4) << 4) | ((v & 8) << 6);
}
__device__ inline int cell_of(float px, float py, float pz) {
    int cx = min(max((int)((px + 1.0f) * 8.0f), 0), 15);
    int cy = min(max((int)((py + 1.0f) * 8.0f), 0), 15);
    int cz = min(max((int)((pz + 1.0f) * 8.0f), 0), 15);
    return spread4(cx) | (spread4(cy) << 1) | (spread4(cz) << 2);
}

// Bricked vox layout: 2x2x2-voxel bricks (8 u32 = 32B), bricks linear in
// (bz,by,bx).  idx = (bz<<13 | by<<8 | bx<<3) + (lz<<2 | ly<<1 | lx).

// ---- fused prep: vox brick-repack + sort histogram + weight prep ----
// Weights FRAGMENT-CONTIGUOUS: w0f[((ks*4+nt)*64 + lane)*8 + j] holds
// W0[(ks*32 + (lane>>4)*8 + j)*64 + nt*16 + (lane&15)] (bf16, 0-pad k>=164).
__global__ void prep_fused(const float* __restrict__ fg, uint4* __restrict__ vox4,
                           const float* __restrict__ x, unsigned short* __restrict__ cid,
                           int* __restrict__ hist,
                           const float* __restrict__ W0, const float* __restrict__ W1,
                           unsigned short* __restrict__ w0f, unsigned short* __restrict__ w1f) {
    int b = blockIdx.x;
    int tid = threadIdx.x;
    if (b < PREP_VB) {
        int idx = b * 256 + tid;            // NG * VOX/4 total
        int g = idx >> 16;
        int hb = idx & 65535;
        int brick = hb >> 1;
        int h = hb & 1;                      // lz
        int bx = brick & 31, by = (brick >> 5) & 31, bz = brick >> 10;
        int xx = bx << 1, yy = by << 1, zz = (bz << 1) + h;
        const float* c0 = fg + (size_t)g * (2 * VOX) + ((zz << 6) + yy) * 64 + xx;
        const float* c1 = c0 + VOX;
        float2 a0 = *(const float2*)c0;
        float2 a1 = *(const float2*)(c0 + 64);
        float2 d0 = *(const float2*)c1;
        float2 d1 = *(const float2*)(c1 + 64);
        vox4[idx] = make_uint4(pk2(a0.x, d0.x), pk2(a0.y, d0.y),
                               pk2(a1.x, d1.x), pk2(a1.y, d1.y));
    } else if (b < PREP_VB + PREP_CB) {
        int p = (b - PREP_VB) * 256 + tid;
        int c = cell_of(x[p * 3 + 0], x[p * 3 + 1], x[p * 3 + 2]);
        cid[p] = (unsigned short)c;
        atomicAdd(&hist[c], 1);
    } else {
        int t = (b - PREP_VB - PREP_CB) * 256 + tid;   // 0..4095
        for (int i = t; i < 24 * 512; i += 4096) {     // w0f: 6ks*4nt*64*8 shorts
            int j = i & 7, ln = (i >> 3) & 63, fi = i >> 9;   // fi = ks*4+nt
            int ks = fi >> 2, nt = fi & 3;
            int k = ks * 32 + ((ln >> 4) << 3) + j, n = nt * 16 + (ln & 15);
            w0f[i] = (k < 164) ? f2bf(W0[k * NODES + n]) : (unsigned short)0;
        }
        {   // w1f: 2ks*4nt*64*8 = 4096 shorts, one per thread
            int i = t;
            int j = i & 7, ln = (i >> 3) & 63, fi = i >> 9;
            int ks = fi >> 2, nt = fi & 3;
            int k = ks * 32 + ((ln >> 4) << 3) + j, n = nt * 16 + (ln & 15);
            w1f[i] = f2bf(W1[k * NODES + n]);
        }
    }
}

// ---- sort 2: exclusive scan of 4096 bins ----
__global__ void sort_scan(const int* __restrict__ hist, int* __restrict__ offs) {
    __shared__ int partial[256];
    int t = threadIdx.x;
    int loc[16];
    int s = 0;
    #pragma unroll
    for (int i = 0; i < 16; ++i) { loc[i] = s; s += hist[t * 16 + i]; }
    partial[t] = s;
    __syncthreads();
    for (int d = 1; d < 256; d <<= 1) {
        int v = (t >= d) ? partial[t - d] : 0;
        __syncthreads();
        partial[t] += v;
        __syncthreads();
    }
    int base = partial[t] - s;      // exclusive
    #pragma unroll
    for (int i = 0; i < 16; ++i) offs[t * 16 + i] = base + loc[i];
}

// ---- sort 3: scatter points to sorted order ----
__global__ void sort_scatter(const float* __restrict__ x, const unsigned short* __restrict__ cell_id,
                             int* __restrict__ offs, float4* __restrict__ spts) {
    int p = blockIdx.x * blockDim.x + threadIdx.x;
    int c = cell_id[p];
    int pos = atomicAdd(&offs[c], 1);
    spts[pos] = make_float4(x[p * 3 + 0], x[p * 3 + 1], x[p * 3 + 2], __int_as_float(p));
}

// ---- gather stage state: one grid, fully register-resident (static names) ----
struct StageG {
    unsigned int c00, c01, c10, c11, c20, c21, c30, c31;  // corners
    float zy00, zy01, zy10, zy11, x0w, x1w;               // weights
    int col;                                              // Fsh short-index
    bool wr;                                              // write predicate
};

// issue one grid: transform, gprep, 8 loads.  All under exec-guard so tail
// slots cost no TA work.  zy products computed at issue (same values/order
// as the original wz*wy -> bit-identical trees).
__device__ __forceinline__ void issue_one(int g, bool part, bool avail,
                                          float px, float py, float pz,
                                          const float* __restrict__ gscale,
                                          const float* __restrict__ gtrans,
                                          const unsigned int* __restrict__ vox,
                                          int ptSF, StageG &S) {
    S.wr = false;
    if (avail) {
        float ix = (px * gscale[g*3+0] + gtrans[g*3+0] + 1.0f) * 31.5f;
        float iy = (py * gscale[g*3+1] + gtrans[g*3+1] + 1.0f) * 31.5f;
        float iz = (pz * gscale[g*3+2] + gtrans[g*3+2] + 1.0f) * 31.5f;
        bool ok = !part || ((ix >= -1.0f) & (ix < 64.0f)
                          & (iy >= -1.0f) & (iy < 64.0f)
                          & (iz >= -1.0f) & (iz < 64.0f));
        if (ok) {
            float fx = floorf(ix), fy = floorf(iy), fz = floorf(iz);
            int x0 = (int)fx, y0 = (int)fy, z0 = (int)fz;
            float wx = ix - fx, wy = iy - fy, wz = iz - fz;
            float wx0 = (x0 >= 0) ? (1.0f - wx) : 0.0f;
            float wx1 = (x0 < 63) ? wx : 0.0f;
            float wy0 = (y0 >= 0) ? (1.0f - wy) : 0.0f;
            float wy1 = (y0 < 63) ? wy : 0.0f;
            float wz0 = (z0 >= 0) ? (1.0f - wz) : 0.0f;
            float wz1 = (z0 < 63) ? wz : 0.0f;
            int xc0 = max(x0, 0), xc1 = min(x0 + 1, 63);
            int yc0 = max(y0, 0), yc1 = min(y0 + 1, 63);
            int zc0 = max(z0, 0), zc1 = min(z0 + 1, 63);
            int xp0 = ((xc0 >> 1) << 3) | (xc0 & 1);
            int xp1 = ((xc1 >> 1) << 3) | (xc1 & 1);
            int yp0 = ((yc0 >> 1) << 8) | ((yc0 & 1) << 1);
            int yp1 = ((yc1 >> 1) << 8) | ((yc1 & 1) << 1);
            int zp0 = ((zc0 >> 1) << 13) | ((zc0 & 1) << 2);
            int zp1 = ((zc1 >> 1) << 13) | ((zc1 & 1) << 2);
            const unsigned int* vg = vox + ((size_t)g << 18);
            S.c00 = vg[zp0 + yp0 + xp0]; S.c01 = vg[zp0 + yp0 + xp1];
            S.c10 = vg[zp0 + yp1 + xp0]; S.c11 = vg[zp0 + yp1 + xp1];
            S.c20 = vg[zp1 + yp0 + xp0]; S.c21 = vg[zp1 + yp0 + xp1];
            S.c30 = vg[zp1 + yp1 + xp0]; S.c31 = vg[zp1 + yp1 + xp1];
            S.zy00 = wz0 * wy0; S.zy01 = wz0 * wy1;
            S.zy10 = wz1 * wy0; S.zy11 = wz1 * wy1;
            S.x0w = wx0; S.x1w = wx1;
            S.col = ptSF + 36 + 2 * g;
            S.wr = true;
        }
    }
}

// evaluate one grid's tree (accumulation order identical to R2-R5 original)
__device__ __forceinline__ void tree_one(const StageG &S, unsigned short* Fsh) {
    if (S.wr) {
        float f0 = 0.f, f1 = 0.f;
        f0 += S.zy00 * (S.x0w * bflo(S.c00) + S.x1w * bflo(S.c01));
        f1 += S.zy00 * (S.x0w * bfhi(S.c00) + S.x1w * bfhi(S.c01));
        f0 += S.zy01 * (S.x0w * bflo(S.c10) + S.x1w * bflo(S.c11));
        f1 += S.zy01 * (S.x0w * bfhi(S.c10) + S.x1w * bfhi(S.c11));
        f0 += S.zy10 * (S.x0w * bflo(S.c20) + S.x1w * bflo(S.c21));
        f1 += S.zy10 * (S.x0w * bfhi(S.c20) + S.x1w * bfhi(S.c21));
        f0 += S.zy11 * (S.x0w * bflo(S.c30) + S.x1w * bflo(S.c31));
        f1 += S.zy11 * (S.x0w * bfhi(S.c30) + S.x1w * bfhi(S.c31));
        *(unsigned int*)&Fsh[S.col] = pk2(f0, f1);
    }
}

#define EXTRACT(gv, pv) \
    if (mf) { gv = (int)__builtin_ctzll(mf); mf &= mf - 1; pv = false; } \
    else if (mp) { gv = (int)__builtin_ctzll(mp); mp &= mp - 1; pv = true; } \
    else { gv = 0; pv = true; }

// extract 8 grids (2 per sub-slot) and issue both of this lane's grids
__device__ __forceinline__ void stage_issue(unsigned long long &mf, unsigned long long &mp,
                                            int done, int total, int sub,
                                            float px, float py, float pz,
                                            const float* __restrict__ gscale,
                                            const float* __restrict__ gtrans,
                                            const unsigned int* __restrict__ vox,
                                            int ptSF, StageG &A, StageG &B) {
    int g0,g1,g2,g3,g4,g5,g6,g7; bool p0,p1,p2,p3,p4,p5,p6,p7;
    EXTRACT(g0,p0) EXTRACT(g1,p1) EXTRACT(g2,p2) EXTRACT(g3,p3)
    EXTRACT(g4,p4) EXTRACT(g5,p5) EXTRACT(g6,p6) EXTRACT(g7,p7)
    int  gA = sub==0?g0: sub==1?g1: sub==2?g2:g3;
    bool pA = sub==0?p0: sub==1?p1: sub==2?p2:p3;
    int  gB = sub==0?g4: sub==1?g5: sub==2?g6:g7;
    bool pB = sub==0?p4: sub==1?p5: sub==2?p6:p7;
    issue_one(gA, pA, (done + sub) < total,     px, py, pz, gscale, gtrans, vox, ptSF, A);
    issue_one(gB, pB, (done + 4 + sub) < total, px, py, pz, gscale, gtrans, vox, ptSF, B);
}

// ---- main fused kernel: BARRIER-FREE (R5) + 2-deep pipelined gather (R6).
// Each wave owns 16 points end-to-end; Fsh rows wave-private; no __syncthreads.
__global__ void __launch_bounds__(256, 5)
amrsrn_main(const float4* __restrict__ spts,
            const float* __restrict__ gscale,
            const float* __restrict__ gtrans,
            const unsigned int* __restrict__ vox,
            const unsigned short* __restrict__ w0f,
            const unsigned short* __restrict__ w1f,
            const float* __restrict__ b0,
            const float* __restrict__ b1,
            const float* __restrict__ W2,
            const float* __restrict__ b2,
            float* __restrict__ out) {
    __shared__ unsigned short Fsh[TILE * SF];   // 25600 B (only LDS) -> 6 blk/CU

    const int tid = threadIdx.x;
    const int lane = tid & 63;
    const int wv = tid >> 6;
    // coarse XCD swizzle: contiguous Morton octant per XCD -> L2 reuse
    const int cb = ((blockIdx.x & 7) << 10) | (blockIdx.x >> 3);
    const int base = cb * TILE;
    const int ptb = wv * 16;
    const int ptloc = lane >> 2;                // 16 points per wave
    const int sub = lane & 3;                   // 4 gather slots per point
    const int pt = ptb + ptloc;

    // ---- own point ----
    float4 sp = spts[base + pt];
    const float px = sp.x, py = sp.y, pz = sp.z;
    const int sreg = __float_as_int(sp.w);

    // ---- zero own 16 Fsh rows ----
    {
        uint4* zp = (uint4*)(Fsh + ptb * SF);
        for (int i = lane; i < 16 * SF / 8; i += 64) zp[i] = make_uint4(0, 0, 0, 0);
    }

    // ---- PE: 16 pts x 36 taus = 64 lanes x 9 ----
    #pragma unroll
    for (int t = 0; t < 9; ++t) {
        int tau = sub * 9 + t;
        int tt = (tau < 18) ? tau : tau - 18;
        int l = tt / 3, d = tt - l * 3;
        float c = (d == 0) ? px : ((d == 1) ? py : pz);
        float ang = c * (3.14159265358979323846f * (float)(1 << l));
        float val = (tau < 18) ? __sinf(ang) : __cosf(ang);
        Fsh[pt * SF + tau] = f2bf(val);
    }

    // ---- wave AABB + grid classification ----
    float lox = px, hix = px, loy = py, hiy = py, loz = pz, hiz = pz;
    #pragma unroll
    for (int m = 1; m < 64; m <<= 1) {
        lox = fminf(lox, __shfl_xor(lox, m)); hix = fmaxf(hix, __shfl_xor(hix, m));
        loy = fminf(loy, __shfl_xor(loy, m)); hiy = fmaxf(hiy, __shfl_xor(hiy, m));
        loz = fminf(loz, __shfl_xor(loz, m)); hiz = fmaxf(hiz, __shfl_xor(hiz, m));
    }
    unsigned long long mf, mp;
    {
        int g = lane;
        float s0 = gscale[g*3+0], s1 = gscale[g*3+1], s2 = gscale[g*3+2];
        float t0 = gtrans[g*3+0], t1 = gtrans[g*3+1], t2 = gtrans[g*3+2];
        float xl = (lox*s0 + t0 + 1.0f)*31.5f, xh = (hix*s0 + t0 + 1.0f)*31.5f;
        float yl = (loy*s1 + t1 + 1.0f)*31.5f, yh = (hiy*s1 + t1 + 1.0f)*31.5f;
        float zl = (loz*s2 + t2 + 1.0f)*31.5f, zh = (hiz*s2 + t2 + 1.0f)*31.5f;
        bool fullg = (xl >= -0.999f) & (xh <= 63.999f)
                   & (yl >= -0.999f) & (yh <= 63.999f)
                   & (zl >= -0.999f) & (zh <= 63.999f);
        bool outg  = (xh < -1.001f) | (xl >= 64.001f)
                   | (yh < -1.001f) | (yl >= 64.001f)
                   | (zh < -1.001f) | (zl >= 64.001f);
        mf = __ballot(fullg);
        mp = __ballot(!fullg && !outg);
    }

    // ---- gathers: 2-deep software pipeline over rounds of 8 grids.
    // Round r+1's loads are issued BEFORE round r's trees -> latency hides
    // under tree VALU + cross-wave TLP.
    {
        int total = __popcll(mf) + __popcll(mp);
        int done = 0;
        const int ptSF = pt * SF;
        StageG A0, B0, A1, B1;
        bool h0 = done < total;
        if (h0) {
            stage_issue(mf, mp, done, total, sub, px, py, pz, gscale, gtrans, vox, ptSF, A0, B0);
            done += 8;
        }
        while (h0) {
            bool h1 = done < total;
            if (h1) {
                stage_issue(mf, mp, done, total, sub, px, py, pz, gscale, gtrans, vox, ptSF, A1, B1);
                done += 8;
            }
            tree_one(A0, Fsh); tree_one(B0, Fsh);
            if (!h1) break;
            h0 = done < total;
            if (h0) {
                stage_issue(mf, mp, done, total, sub, px, py, pz, gscale, gtrans, vox, ptSF, A0, B0);
                done += 8;
            }
            tree_one(A1, Fsh); tree_one(B1, Fsh);
        }
    }

    // ---- MFMA MLP on own 16 rows (same-wave, no barrier) ----
    const int row = lane & 15;
    const int quad = lane >> 4;

    f32x4 acc0[4] = {{0,0,0,0},{0,0,0,0},{0,0,0,0},{0,0,0,0}};
    #pragma unroll
    for (int ks = 0; ks < 6; ++ks) {
        bf16x8 a = *(const bf16x8*)&Fsh[(ptb + row) * SF + ks * 32 + quad * 8];
        #pragma unroll
        for (int nt = 0; nt < 4; ++nt) {
            bf16x8 b = *(const bf16x8*)&w0f[(((ks << 2) + nt) << 9) + (lane << 3)];
            acc0[nt] = __builtin_amdgcn_mfma_f32_16x16x32_bf16(a, b, acc0[nt], 0, 0, 0);
        }
    }
    #pragma unroll
    for (int nt = 0; nt < 4; ++nt) {
        int node = nt * 16 + row;
        float bb = b0[node];
        #pragma unroll
        for (int r = 0; r < 4; ++r) {
            float h = acc0[nt][r] + bb;
            float s = __sinf(h);
            h = 0.5f * h + s * s;
            Fsh[(ptb + quad * 4 + r) * SF + node] = f2bf(h);
        }
    }

    f32x4 acc1[4] = {{0,0,0,0},{0,0,0,0},{0,0,0,0},{0,0,0,0}};
    #pragma unroll
    for (int ks = 0; ks < 2; ++ks) {
        bf16x8 a = *(const bf16x8*)&Fsh[(ptb + row) * SF + ks * 32 + quad * 8];
        #pragma unroll
        for (int nt = 0; nt < 4; ++nt) {
            bf16x8 b = *(const bf16x8*)&w1f[(((ks << 2) + nt) << 9) + (lane << 3)];
            acc1[nt] = __builtin_amdgcn_mfma_f32_16x16x32_bf16(a, b, acc1[nt], 0, 0, 0);
        }
    }
    float part[4] = {0.f, 0.f, 0.f, 0.f};
    #pragma unroll
    for (int nt = 0; nt < 4; ++nt) {
        int node = nt * 16 + row;
        float b1v = b1[node];
        float w2v = W2[node];
        #pragma unroll
        for (int r = 0; r < 4; ++r) {
            float h = acc1[nt][r] + b1v;
            float s = __sinf(h);
            h = 0.5f * h + s * s;
            part[r] += h * w2v;
        }
    }
    #pragma unroll
    for (int m = 1; m < 16; m <<= 1) {
        #pragma unroll
        for (int r = 0; r < 4; ++r) part[r] += __shfl_xor(part[r], m);
    }
    int o0 = __shfl(sreg, (quad * 4 + 0) << 2);
    int o1 = __shfl(sreg, (quad * 4 + 1) << 2);
    int o2 = __shfl(sreg, (quad * 4 + 2) << 2);
    int o3 = __shfl(sreg, (quad * 4 + 3) << 2);
    if (row == 0) {
        float b2v = b2[0];
        out[o0] = part[0] + b2v;
        out[o1] = part[1] + b2v;
        out[o2] = part[2] + b2v;
        out[o3] = part[3] + b2v;
    }
}

// ---- fallback (no workspace): direct fp32 kernel ----
__global__ void amrsrn_fallback(const float* __restrict__ x,
                                const float* __restrict__ gscale,
                                const float* __restrict__ gtrans,
                                const float* __restrict__ fg,
                                const float* __restrict__ W0,
                                const float* __restrict__ b0,
                                const float* __restrict__ W1,
                                const float* __restrict__ b1,
                                const float* __restrict__ W2,
                                const float* __restrict__ b2,
                                float* __restrict__ out) {
    int p = blockIdx.x * blockDim.x + threadIdx.x;
    float px = x[p*3+0], py = x[p*3+1], pz = x[p*3+2];
    float h0[NODES];
    #pragma unroll
    for (int j = 0; j < NODES; ++j) h0[j] = b0[j];
    #pragma unroll
    for (int l = 0; l < 6; ++l) {
        float freq = 3.14159265358979323846f * (float)(1 << l);
        #pragma unroll
        for (int d = 0; d < 3; ++d) {
            float v = (d == 0 ? px : (d == 1 ? py : pz)) * freq;
            float s = __sinf(v), c = __cosf(v);
            const float* wrs = W0 + (l*3 + d) * NODES;
            const float* wrc = W0 + (18 + l*3 + d) * NODES;
            #pragma unroll
            for (int j = 0; j < NODES; ++j) h0[j] += s * wrs[j] + c * wrc[j];
        }
    }
    for (int g = 0; g < NG; ++g) {
        float ix = (px * gscale[g*3+0] + gtrans[g*3+0] + 1.0f) * 31.5f;
        float iy = (py * gscale[g*3+1] + gtrans[g*3+1] + 1.0f) * 31.5f;
        float iz = (pz * gscale[g*3+2] + gtrans[g*3+2] + 1.0f) * 31.5f;
        float fxf = floorf(ix), fyf = floorf(iy), fzf = floorf(iz);
        int x0 = (int)fxf, y0 = (int)fyf, z0 = (int)fzf;
        float wx = ix - fxf, wy = iy - fyf, wz = iz - fzf;
        bool any = (x0 >= -1 && x0 < GSZ) && (y0 >= -1 && y0 < GSZ) && (z0 >= -1 && z0 < GSZ);
        if (any) {
            float f0 = 0.f, f1 = 0.f;
            #pragma unroll
            for (int dz = 0; dz < 2; ++dz) {
                int zi = z0 + dz; bool vz = ((unsigned)zi < (unsigned)GSZ);
                int zc = min(max(zi, 0), GSZ - 1);
                float wzf = dz ? wz : 1.f - wz;
                #pragma unroll
                for (int dy = 0; dy < 2; ++dy) {
                    int yi = y0 + dy; bool vy = ((unsigned)yi < (unsigned)GSZ);
                    int yc = min(max(yi, 0), GSZ - 1);
                    float wyf = dy ? wy : 1.f - wy;
                    int rowoff = (zc * GSZ + yc) * GSZ;
                    #pragma unroll
                    for (int dx = 0; dx < 2; ++dx) {
                        int xi = x0 + dx; bool vx = ((unsigned)xi < (unsigned)GSZ);
                        int xc = min(max(xi, 0), GSZ - 1);
                        float w = wzf * wyf * (dx ? wx : 1.f - wx);
                        w = (vz && vy && vx) ? w : 0.f;
                        const float* gp = fg + ((size_t)g << 19);
                        f0 += w * gp[rowoff + xc];
                        f1 += w * gp[VOX + rowoff + xc];
                    }
                }
            }
            const float* wr = W0 + (36 + 2*g) * NODES;
            #pragma unroll
            for (int j = 0; j < NODES; ++j) h0[j] += f0 * wr[j] + f1 * wr[NODES + j];
        }
    }
    #pragma unroll
    for (int j = 0; j < NODES; ++j) { float s = __sinf(h0[j]); h0[j] = 0.5f * h0[j] + s * s; }
    float out_acc = b2[0];
    #pragma unroll
    for (int half = 0; half < 2; ++half) {
        float h1[32];
        #pragma unroll
        for (int j = 0; j < 32; ++j) h1[j] = b1[half*32 + j];
        #pragma unroll
        for (int i = 0; i < NODES; ++i) {
            float a = h0[i];
            const float* w1r = W1 + i * NODES + half*32;
            #pragma unroll
            for (int j = 0; j < 32; ++j) h1[j] += a * w1r[j];
        }
        #pragma unroll
        for (int j = 0; j < 32; ++j) { float s = __sinf(h1[j]); out_acc += (0.5f * h1[j] + s * s) * W2[half*32 + j]; }
    }
    out[p] = out_acc;
}

extern "C" void kernel_launch(void* const* d_in, const int* in_sizes, int n_in,
                              void* d_out, int out_size, void* d_ws, size_t ws_size,
                              hipStream_t stream) {
    const float* x      = (const float*)d_in[0];
    const float* gscale = (const float*)d_in[1];
    const float* gtrans = (const float*)d_in[2];
    const float* fg     = (const float*)d_in[3];
    const float* W0     = (const float*)d_in[4];
    const float* b0     = (const float*)d_in[5];
    const float* W1     = (const float*)d_in[6];
    const float* b1     = (const float*)d_in[7];
    const float* W2     = (const float*)d_in[8];
    const float* b2     = (const float*)d_in[9];
    float* out = (float*)d_out;

    char* wsp = (char*)d_ws;
    unsigned short* w0f = (unsigned short*)wsp;            // 24576 B
    unsigned short* w1f = w0f + 24 * 512;                  // 8192 B
    int* hist           = (int*)(wsp + (64 << 10));
    int* offs           = (int*)(wsp + (80 << 10));
    unsigned short* cid = (unsigned short*)(wsp + (96 << 10));
    float4* spts        = (float4*)(wsp + (96 << 10) + (1 << 20));
    unsigned int* vox   = (unsigned int*)(wsp + (96 << 10) + (1 << 20) + (8 << 20));
    const size_t ws_needed = (96 << 10) + (1 << 20) + (8 << 20) + (size_t)NG * VOX * 4;

    if (ws_size >= ws_needed) {
        hipMemsetAsync(hist, 0, NCELL * sizeof(int), stream);
        prep_fused<<<PREP_VB + PREP_CB + 16, 256, 0, stream>>>(
            fg, (uint4*)vox, x, cid, hist, W0, W1, w0f, w1f);
        sort_scan<<<1, 256, 0, stream>>>(hist, offs);
        sort_scatter<<<NPTS / 256, 256, 0, stream>>>(x, cid, offs, spts);
        amrsrn_main<<<NBLK, 256, 0, stream>>>(spts, gscale, gtrans, vox,
                                              w0f, w1f, b0, b1, W2, b2, out);
    } else {
        amrsrn_fallback<<<NPTS / 256, 256, 0, stream>>>(
            x, gscale, gtrans, fg, W0, b0, W1, b1, W2, b2, out);
    }
}